// Round 5
// baseline (122.274 us; speedup 1.0000x reference)
//
#include <hip/hip_runtime.h>
#include <math.h>

#define EPSF    1e-8f
#define SLOPEF  0.2f
#define GS_EPSF 1e-6f

#define NB   4
#define KZ   4
#define BKT  16     // NB*KZ
#define NPT  2048
#define DIM  32

#define COMP(v,kk) ((kk)==0?(v).x:(kk)==1?(v).y:(kk)==2?(v).z:(v).w)

__device__ __forceinline__ void fma4(float4& acc, float s, const float4& v) {
  acc.x = fmaf(s, v.x, acc.x); acc.y = fmaf(s, v.y, acc.y);
  acc.z = fmaf(s, v.z, acc.z); acc.w = fmaf(s, v.w, acc.w);
}

// ---------------------------------------------------------------------------
// Kernel 0: pts[bk*2048+n] = {A=(ch0,ch1,ch2,ch3), B=(ch4,ch5,xx,0)} interleaved
// ---------------------------------------------------------------------------
__global__ __launch_bounds__(256) void prep_coords(
    const float* __restrict__ node, const float* __restrict__ z,
    float4* __restrict__ pts) {
  int t = blockIdx.x * 256 + threadIdx.x;
  if (t >= BKT * NPT) return;
  int bk = t >> 11, n = t & (NPT - 1);
  int b = bk >> 2, kz = bk & 3;
  const float2* np2 = (const float2*)(node + (size_t)(b * NPT + n) * 6);
  const float2* zp2 = (const float2*)(z + (size_t)((b * KZ + kz) * NPT + n) * 6);
  float ch[6];
#pragma unroll
  for (int j = 0; j < 3; ++j) {
    float2 a = np2[j], c = zp2[j];
    ch[j]     = a.x + c.x;
    ch[3 + j] = a.y + c.y;
  }
  float xx = 0.f;
#pragma unroll
  for (int h = 0; h < 6; ++h) xx = fmaf(ch[h], ch[h], xx);
  pts[(size_t)t * 2 + 0] = make_float4(ch[0], ch[1], ch[2], ch[3]);
  pts[(size_t)t * 2 + 1] = make_float4(ch[4], ch[5], xx, 0.f);
}

// ---------------------------------------------------------------------------
// branchless sorted-insert of (s,j) into desc top-3; ascending-j + strict '>'
// ---------------------------------------------------------------------------
__device__ __forceinline__ void ins3(float s, int j,
    float& v0, float& v1, float& v2, int& i0, int& i1, int& i2) {
  bool c2 = s > v2;
  float nv2 = c2 ? s : v2; int ni2 = c2 ? j : i2;
  bool c1 = nv2 > v1;
  float u1v = c1 ? nv2 : v1, u2v = c1 ? v1 : nv2;
  int   u1i = c1 ? ni2 : i1, u2i = c1 ? i1 : ni2;
  bool c0 = u1v > v0;
  v1 = c0 ? v0 : u1v; i1 = c0 ? i0 : u1i;
  v0 = c0 ? u1v : v0; i0 = c0 ? u1i : i0;
  v2 = u2v; i2 = u2i;
}

// compare-exchange: total order (value desc, index asc)
__device__ __forceinline__ void ce(float& vx, int& ix, float& vy, int& iy) {
  float av = vx, bv = vy; int ai = ix, bi = iy;
  bool sw = (bv > av) || (bv == av && bi < ai);
  vx = sw ? bv : av; vy = sw ? av : bv;
  ix = sw ? bi : ai; iy = sw ? ai : bi;
}

__device__ __forceinline__ float score7(const float4& qa, const float4& qb,
                                        const float4& A, const float4& B) {
  float s = qa.x * A.x;
  s = fmaf(qa.y, A.y, s);
  s = fmaf(qa.z, A.z, s);
  s = fmaf(qa.w, A.w, s);
  s = fmaf(qb.x, B.x, s);
  s = fmaf(qb.y, B.y, s);
  s = fmaf(-0.5f, B.z, s);
  return s;
}

// 256-point scan with register double-buffer prefetch + 2 independent chains
template <bool SELF>
__device__ __forceinline__ void scan256(const float4* __restrict__ pp, int j0, int q,
    const float4 qa, const float4 qb,
    float& v0, float& v1, float& v2, int& i0, int& i1, int& i2) {
  float w0 = -INFINITY, w1 = -INFINITY, w2 = -INFINITY;
  int   k0 = 0x7fffffff, k1 = 0x7fffffff, k2 = 0x7fffffff;
  float4 A[8], Bv[8];
#pragma unroll
  for (int u = 0; u < 8; ++u) { A[u] = pp[2 * u]; Bv[u] = pp[2 * u + 1]; }
  for (int t = 0; t < 256; t += 8) {
    float s[8];
#pragma unroll
    for (int u = 0; u < 8; ++u) s[u] = score7(qa, qb, A[u], Bv[u]);
    if (SELF) {
#pragma unroll
      for (int u = 0; u < 8; ++u) if (j0 + t + u == q) s[u] = -INFINITY;
    }
    if (t + 8 < 256) {            // prefetch next group before inserts
      const float4* np = pp + 2 * (t + 8);
#pragma unroll
      for (int u = 0; u < 8; ++u) { A[u] = np[2 * u]; Bv[u] = np[2 * u + 1]; }
    }
    ins3(s[0], j0 + t + 0, v0, v1, v2, i0, i1, i2);
    ins3(s[1], j0 + t + 1, v0, v1, v2, i0, i1, i2);
    ins3(s[2], j0 + t + 2, v0, v1, v2, i0, i1, i2);
    ins3(s[3], j0 + t + 3, v0, v1, v2, i0, i1, i2);
    ins3(s[4], j0 + t + 4, w0, w1, w2, k0, k1, k2);
    ins3(s[5], j0 + t + 5, w0, w1, w2, k0, k1, k2);
    ins3(s[6], j0 + t + 6, w0, w1, w2, k0, k1, k2);
    ins3(s[7], j0 + t + 7, w0, w1, w2, k0, k1, k2);
  }
  // bitonic merge of the two sorted top-3 lists (half-cleaner + sort3)
  ce(v0, i0, w2, k2); ce(v1, i1, w1, k1); ce(v2, i2, w0, k0);
  ce(v0, i0, v1, i1); ce(v1, i1, v2, i2); ce(v0, i0, v1, i1);
}

// ---------------------------------------------------------------------------
// Kernel 1: full KNN per block. Block = 64 queries x 8 waves; wave w scans its
// 256-point segment (wave-uniform addresses). Self is always top-1 -> scan
// top-3 of j!=q, prepend q. LDS tree merge -> knn4.
// ---------------------------------------------------------------------------
__global__ __launch_bounds__(512, 4) void knn_kernel(
    const float4* __restrict__ pts, int4* __restrict__ knn4) {
  __shared__ float4 lv[8][64];
  __shared__ int4   li[8][64];
  int lane = threadIdx.x & 63;
  int w = threadIdx.x >> 6;                 // segment 0..7
  int bk = blockIdx.x >> 5, qg = blockIdx.x & 31;
  int base = bk * NPT;
  int q = qg * 64 + lane;
  float4 qa = pts[(size_t)(base + q) * 2 + 0];
  float4 qb = pts[(size_t)(base + q) * 2 + 1];
  int j0 = __builtin_amdgcn_readfirstlane(w * 256);
  const float4* pp = pts + ((size_t)base + j0) * 2;
  float v0 = -INFINITY, v1 = -INFINITY, v2 = -INFINITY;
  int   i0 = 0x7fffffff, i1 = 0x7fffffff, i2 = 0x7fffffff;
  if (w == (qg >> 2)) scan256<true >(pp, j0, q, qa, qb, v0, v1, v2, i0, i1, i2);
  else                scan256<false>(pp, j0, q, qa, qb, v0, v1, v2, i0, i1, i2);
  lv[w][lane] = make_float4(v0, v1, v2, -INFINITY);
  li[w][lane] = make_int4(i0, i1, i2, 0x7fffffff);
  __syncthreads();
#pragma unroll
  for (int str = 4; str >= 1; str >>= 1) {
    if (w < str) {
      float4 av = lv[w][lane];        int4 ai = li[w][lane];
      float4 bv = lv[w + str][lane];  int4 bi = li[w + str][lane];
      float a0 = av.x, a1 = av.y, a2 = av.z, a3 = av.w;
      int   c0 = ai.x, c1 = ai.y, c2 = ai.z, c3 = ai.w;
      float s4 = bv.w, s5 = bv.z, s6 = bv.y, s7 = bv.x;
      int   t4 = bi.w, t5 = bi.z, t6 = bi.y, t7 = bi.x;
      ce(a0, c0, s4, t4); ce(a1, c1, s5, t5);
      ce(a2, c2, s6, t6); ce(a3, c3, s7, t7);
      ce(a0, c0, a2, c2); ce(a1, c1, a3, c3);
      ce(a0, c0, a1, c1); ce(a2, c2, a3, c3);
      lv[w][lane] = make_float4(a0, a1, a2, a3);
      li[w][lane] = make_int4(c0, c1, c2, c3);
    }
    __syncthreads();
  }
  if (w == 0) {
    int4 r = li[0][lane];
    knn4[base + q] = make_int4(q, r.x, r.y, r.z);
  }
}

// ---------------------------------------------------------------------------
// Kernel 2: 16 points/block, thread = (p 0..15, og 0..7), o = og+8m (m 0..3).
// h (kk-packed f4 in LDS) -> d1 (packed) -> argmax k -> x1 -> d3 -> dot3 ->
// block argmax over 16 pts -> partials[bk][o][pb] = (x1, dot3)
// ---------------------------------------------------------------------------
__global__ __launch_bounds__(128, 2) void feature_kernel(
    const float4* __restrict__ pts, const int4* __restrict__ knn4,
    const float* __restrict__ W1f, const float* __restrict__ W1d,
    const float* __restrict__ Wp1, const float* __restrict__ Wp3,
    float4* __restrict__ partials) {
  __shared__ float4 hlds[16][97];          // [p][c*3+j] : f4 over kk (pad 1)
  __shared__ float4 x1lds[16][33];         // [p][c] : (x1, dot3-in-w)
  __shared__ float4 wp1P[256], wp3P[256];  // [c*8+og] = W[og+8m][c] over m
  for (int i = threadIdx.x; i < 256; i += 128) {
    int ogs = i & 7, c = i >> 3;
    wp1P[i] = make_float4(Wp1[ogs * 32 + c], Wp1[(ogs + 8) * 32 + c],
                          Wp1[(ogs + 16) * 32 + c], Wp1[(ogs + 24) * 32 + c]);
    wp3P[i] = make_float4(Wp3[ogs * 32 + c], Wp3[(ogs + 8) * 32 + c],
                          Wp3[(ogs + 16) * 32 + c], Wp3[(ogs + 24) * 32 + c]);
  }
  int p = threadIdx.x >> 3;        // 0..15
  int og = threadIdx.x & 7;        // o = og + 8m
  int bk = blockIdx.x >> 7, pb = blockIdx.x & 127;
  int n = (pb << 4) | p;
  int base = bk * NPT;
  float4 ca = pts[(size_t)(base + n) * 2 + 0], cbv = pts[(size_t)(base + n) * 2 + 1];
  float ct[6] = {ca.x, ca.y, ca.z, ca.w, cbv.x, cbv.y};
  float w1f[4][4], w1d[4][4];
#pragma unroll
  for (int m = 0; m < 4; ++m) {
    float4 wf = reinterpret_cast<const float4*>(W1f)[og + 8 * m];
    float4 wd = reinterpret_cast<const float4*>(W1d)[og + 8 * m];
    w1f[m][0] = wf.x; w1f[m][1] = wf.y; w1f[m][2] = wf.z; w1f[m][3] = wf.w;
    w1d[m][0] = wd.x; w1d[m][1] = wd.y; w1d[m][2] = wd.z; w1d[m][3] = wd.w;
  }
  int4 nb = knn4[base + n];
  int nbi[4] = {nb.x, nb.y, nb.z, nb.w};
  float h[4][4][3];                // [m][kk][j]
#pragma unroll
  for (int kk = 0; kk < 4; ++kk) {
    int mi = nbi[kk];
    float4 A = pts[(size_t)(base + mi) * 2 + 0], B = pts[(size_t)(base + mi) * 2 + 1];
    float nc[6] = {A.x, A.y, A.z, A.w, B.x, B.y};
    float G[4][3];
#pragma unroll
    for (int j = 0; j < 3; ++j) {
      G[0][j] = nc[j] - ct[j];
      G[1][j] = nc[3 + j] - ct[3 + j];
      G[2][j] = ct[j];
      G[3][j] = ct[3 + j];
    }
#pragma unroll
    for (int m = 0; m < 4; ++m) {
      float pvv[3], dv[3];
#pragma unroll
      for (int j = 0; j < 3; ++j) {
        float a = 0.f, dd = 0.f;
#pragma unroll
        for (int c = 0; c < 4; ++c) { a = fmaf(w1f[m][c], G[c][j], a); dd = fmaf(w1d[m][c], G[c][j], dd); }
        pvv[j] = a; dv[j] = dd;
      }
      float dot = pvv[0] * dv[0] + pvv[1] * dv[1] + pvv[2] * dv[2];
      float d2  = dv[0] * dv[0] + dv[1] * dv[1] + dv[2] * dv[2];
      float fac = dot / (d2 + EPSF);
#pragma unroll
      for (int j = 0; j < 3; ++j) {
        float negj = pvv[j] - fac * dv[j];
        float sel = (dot >= 0.f) ? pvv[j] : negj;
        h[m][kk][j] = SLOPEF * pvv[j] + (1.f - SLOPEF) * sel;
      }
    }
  }
#pragma unroll
  for (int m = 0; m < 4; ++m)
#pragma unroll
    for (int j = 0; j < 3; ++j)
      hlds[p][(og + 8 * m) * 3 + j] =
          make_float4(h[m][0][j], h[m][1][j], h[m][2][j], h[m][3][j]);
  __syncthreads();
  // d1[m][j] (f4 over kk) = sum_c Wp1[og+8m][c] * h[c][kk][j]
  float4 d1j0[4], d1j1[4], d1j2[4];
#pragma unroll
  for (int m = 0; m < 4; ++m) {
    d1j0[m] = make_float4(0.f, 0.f, 0.f, 0.f);
    d1j1[m] = make_float4(0.f, 0.f, 0.f, 0.f);
    d1j2[m] = make_float4(0.f, 0.f, 0.f, 0.f);
  }
  for (int c = 0; c < 32; ++c) {
    float4 wv = wp1P[c * 8 + og];
    float4 h0 = hlds[p][c * 3 + 0];
    float4 h1 = hlds[p][c * 3 + 1];
    float4 h2 = hlds[p][c * 3 + 2];
#pragma unroll
    for (int m = 0; m < 4; ++m) {
      float wm = COMP(wv, m);
      fma4(d1j0[m], wm, h0);
      fma4(d1j1[m], wm, h1);
      fma4(d1j2[m], wm, h2);
    }
  }
  // argmax over kk (first occurrence), per m
  float x1[4][3];
#pragma unroll
  for (int m = 0; m < 4; ++m) {
    float best = -INFINITY;
    float xa = 0.f, xb = 0.f, xc = 0.f;
#pragma unroll
    for (int kk = 0; kk < 4; ++kk) {
      float dt = h[m][kk][0] * COMP(d1j0[m], kk)
               + h[m][kk][1] * COMP(d1j1[m], kk)
               + h[m][kk][2] * COMP(d1j2[m], kk);
      if (dt > best) { best = dt; xa = h[m][kk][0]; xb = h[m][kk][1]; xc = h[m][kk][2]; }
    }
    x1[m][0] = xa; x1[m][1] = xb; x1[m][2] = xc;
    x1lds[p][og + 8 * m] = make_float4(xa, xb, xc, 0.f);
  }
  __syncthreads();
  float d3[4][3] = {};
  for (int c = 0; c < 32; ++c) {
    float4 wv = wp3P[c * 8 + og];
    float4 xv = x1lds[p][c];
#pragma unroll
    for (int m = 0; m < 4; ++m) {
      float wm = COMP(wv, m);
      d3[m][0] = fmaf(wm, xv.x, d3[m][0]);
      d3[m][1] = fmaf(wm, xv.y, d3[m][1]);
      d3[m][2] = fmaf(wm, xv.z, d3[m][2]);
    }
  }
#pragma unroll
  for (int m = 0; m < 4; ++m) {
    float dot3 = x1[m][0] * d3[m][0] + x1[m][1] * d3[m][1] + x1[m][2] * d3[m][2];
    x1lds[p][og + 8 * m].w = dot3;
  }
  __syncthreads();
  if (threadIdx.x < 32) {
    int o = threadIdx.x;
    float bd = -INFINITY; int wp_ = 0;
#pragma unroll
    for (int p2 = 0; p2 < 16; ++p2) {
      float dv = x1lds[p2][o].w;
      if (dv > bd) { bd = dv; wp_ = p2; }      // strict '>': first n wins
    }
    float4 xv = x1lds[wp_][o];
    partials[(((size_t)(bk * 32 + o)) << 7) | pb] = make_float4(xv.x, xv.y, xv.z, bd);
  }
}

// ---------------------------------------------------------------------------
// Kernel 3: per bk: argmax over 128 partials per o (first-index ties), then
// head: pk = Wh2 @ pooled ; +GS_EPS*noise ; Gram-Schmidt ; det flip
// ---------------------------------------------------------------------------
__global__ __launch_bounds__(256) void poolhead_kernel(
    const float4* __restrict__ partials, const float* __restrict__ Wh2,
    const float* __restrict__ gs, float* __restrict__ out) {
  __shared__ float pl[DIM][3];
  int bk = blockIdx.x;
  int o = threadIdx.x >> 3, tg = threadIdx.x & 7;
  const float4* pp = partials + (((size_t)(bk * 32 + o)) << 7);
  float best = -INFINITY; int bp = 0x7fffffff;
  for (int t = 0; t < 16; ++t) {
    int pb = t * 8 + tg;
    float v = pp[pb].w;
    if (v > best) { best = v; bp = pb; }       // strict '>' within residue class
  }
#pragma unroll
  for (int off = 1; off < 8; off <<= 1) {
    float ov = __shfl_xor(best, off, 8);
    int   op = __shfl_xor(bp, off, 8);
    if (ov > best || (ov == best && op < bp)) { best = ov; bp = op; }
  }
  if (tg == 0) {
    float4 xv = pp[bp];
    pl[o][0] = xv.x; pl[o][1] = xv.y; pl[o][2] = xv.z;
  }
  __syncthreads();
  if (threadIdx.x == 0) {
    float M[3][3];
#pragma unroll
    for (int oo = 0; oo < 3; ++oo) {
      float a0 = 0.f, a1 = 0.f, a2 = 0.f;
      for (int c = 0; c < 32; ++c) {
        float w = Wh2[oo * 32 + c];
        a0 = fmaf(w, pl[c][0], a0);
        a1 = fmaf(w, pl[c][1], a1);
        a2 = fmaf(w, pl[c][2], a2);
      }
      M[0][oo] = a0 + GS_EPSF * gs[bk * 9 + 0 * 3 + oo];
      M[1][oo] = a1 + GS_EPSF * gs[bk * 9 + 1 * 3 + oo];
      M[2][oo] = a2 + GS_EPSF * gs[bk * 9 + 2 * 3 + oo];
    }
    float e1[3], e2[3], e3[3], u[3];
    float nn = sqrtf(M[0][0] * M[0][0] + M[1][0] * M[1][0] + M[2][0] * M[2][0]) + EPSF;
#pragma unroll
    for (int r = 0; r < 3; ++r) e1[r] = M[r][0] / nn;
    float d12 = e1[0] * M[0][1] + e1[1] * M[1][1] + e1[2] * M[2][1];
#pragma unroll
    for (int r = 0; r < 3; ++r) u[r] = M[r][1] - d12 * e1[r];
    nn = sqrtf(u[0] * u[0] + u[1] * u[1] + u[2] * u[2]) + EPSF;
#pragma unroll
    for (int r = 0; r < 3; ++r) e2[r] = u[r] / nn;
    float d13 = e1[0] * M[0][2] + e1[1] * M[1][2] + e1[2] * M[2][2];
    float d23 = e2[0] * M[0][2] + e2[1] * M[1][2] + e2[2] * M[2][2];
#pragma unroll
    for (int r = 0; r < 3; ++r) u[r] = M[r][2] - d13 * e1[r] - d23 * e2[r];
    nn = sqrtf(u[0] * u[0] + u[1] * u[1] + u[2] * u[2]) + EPSF;
#pragma unroll
    for (int r = 0; r < 3; ++r) e3[r] = u[r] / nn;
    float det = e1[0] * (e2[1] * e3[2] - e2[2] * e3[1])
              - e1[1] * (e2[0] * e3[2] - e2[2] * e3[0])
              + e1[2] * (e2[0] * e3[1] - e2[1] * e3[0]);
#pragma unroll
    for (int r = 0; r < 3; ++r) {
      out[bk * 9 + r * 3 + 0] = e1[r] * det;
      out[bk * 9 + r * 3 + 1] = e2[r];
      out[bk * 9 + r * 3 + 2] = e3[r];
    }
  }
}

// ---------------------------------------------------------------------------
extern "C" void kernel_launch(void* const* d_in, const int* in_sizes, int n_in,
                              void* d_out, int out_size, void* d_ws, size_t ws_size,
                              hipStream_t stream) {
  (void)in_sizes; (void)n_in; (void)out_size; (void)ws_size;
  const float* node = (const float*)d_in[0];
  const float* W1f = (const float*)d_in[4];
  const float* W1d = (const float*)d_in[5];
  const float* Wp1 = (const float*)d_in[6];
  const float* Wp3 = (const float*)d_in[7];
  const float* Wh2 = (const float*)d_in[8];
  const float* z   = (const float*)d_in[9];
  const float* gs  = (const float*)d_in[10];

  float4* pts      = (float4*)d_ws;                          // 65536 f4 = 1 MB
  int4*   knn4     = (int4*)(pts + (size_t)BKT * NPT * 2);   // 512 KB
  float4* partials = (float4*)(knn4 + (size_t)BKT * NPT);    // 16*32*128 f4 = 1 MB
  float*  out      = (float*)d_out;

  prep_coords    <<<BKT * NPT / 256, 256, 0, stream>>>(node, z, pts);
  knn_kernel     <<<BKT * 32, 512, 0, stream>>>(pts, knn4);
  feature_kernel <<<BKT * 128, 128, 0, stream>>>(pts, knn4, W1f, W1d, Wp1, Wp3, partials);
  poolhead_kernel<<<BKT, 256, 0, stream>>>(partials, Wh2, gs, out);
}

// Round 6
// 87.910 us; speedup vs baseline: 1.3909x; 1.3909x over previous
//
#include <hip/hip_runtime.h>
#include <math.h>

#define EPSF    1e-8f
#define SLOPEF  0.2f
#define GS_EPSF 1e-6f

#define NB   4
#define KZ   4
#define BKT  16     // NB*KZ
#define NPT  2048
#define DIM  32

#define COMP(v,kk) ((kk)==0?(v).x:(kk)==1?(v).y:(kk)==2?(v).z:(v).w)

__device__ __forceinline__ void fma4(float4& acc, float s, const float4& v) {
  acc.x = fmaf(s, v.x, acc.x); acc.y = fmaf(s, v.y, acc.y);
  acc.z = fmaf(s, v.z, acc.z); acc.w = fmaf(s, v.w, acc.w);
}

// ---------------------------------------------------------------------------
// Kernel 0: pts[bk*2048+n] = {A=(ch0..ch3), B=(ch4,ch5,xx,0)} interleaved.
// Block 0 additionally packs Wp1/Wp3 into wpk: wpk[c*8+og] = Wp1[og+8m][c]
// over m (f4), wpk[256 + c*8+og] likewise for Wp3.
// ---------------------------------------------------------------------------
__global__ __launch_bounds__(256) void prep_coords(
    const float* __restrict__ node, const float* __restrict__ z,
    const float* __restrict__ Wp1, const float* __restrict__ Wp3,
    float4* __restrict__ pts, float4* __restrict__ wpk) {
  if (blockIdx.x == 0) {
    int i = threadIdx.x;                   // 256 entries each
    int og = i & 7, c = i >> 3;
    wpk[i]       = make_float4(Wp1[og * 32 + c], Wp1[(og + 8) * 32 + c],
                               Wp1[(og + 16) * 32 + c], Wp1[(og + 24) * 32 + c]);
    wpk[256 + i] = make_float4(Wp3[og * 32 + c], Wp3[(og + 8) * 32 + c],
                               Wp3[(og + 16) * 32 + c], Wp3[(og + 24) * 32 + c]);
  }
  int t = blockIdx.x * 256 + threadIdx.x;
  if (t >= BKT * NPT) return;
  int bk = t >> 11, n = t & (NPT - 1);
  int b = bk >> 2, kz = bk & 3;
  const float2* np2 = (const float2*)(node + (size_t)(b * NPT + n) * 6);
  const float2* zp2 = (const float2*)(z + (size_t)((b * KZ + kz) * NPT + n) * 6);
  float ch[6];
#pragma unroll
  for (int j = 0; j < 3; ++j) {
    float2 a = np2[j], c = zp2[j];
    ch[j]     = a.x + c.x;
    ch[3 + j] = a.y + c.y;
  }
  float xx = 0.f;
#pragma unroll
  for (int h = 0; h < 6; ++h) xx = fmaf(ch[h], ch[h], xx);
  pts[(size_t)t * 2 + 0] = make_float4(ch[0], ch[1], ch[2], ch[3]);
  pts[(size_t)t * 2 + 1] = make_float4(ch[4], ch[5], xx, 0.f);
}

// ---------------------------------------------------------------------------
// branchless sorted-insert of (s,j) into desc top-3; ascending-j + strict '>'
// ---------------------------------------------------------------------------
__device__ __forceinline__ void ins3(float s, int j,
    float& v0, float& v1, float& v2, int& i0, int& i1, int& i2) {
  bool c2 = s > v2;
  float nv2 = c2 ? s : v2; int ni2 = c2 ? j : i2;
  bool c1 = nv2 > v1;
  float u1v = c1 ? nv2 : v1, u2v = c1 ? v1 : nv2;
  int   u1i = c1 ? ni2 : i1, u2i = c1 ? i1 : ni2;
  bool c0 = u1v > v0;
  v1 = c0 ? v0 : u1v; i1 = c0 ? i0 : u1i;
  v0 = c0 ? u1v : v0; i0 = c0 ? u1i : i0;
  v2 = u2v; i2 = u2i;
}

// compare-exchange: total order (value desc, index asc)
__device__ __forceinline__ void ce(float& vx, int& ix, float& vy, int& iy) {
  float av = vx, bv = vy; int ai = ix, bi = iy;
  bool sw = (bv > av) || (bv == av && bi < ai);
  vx = sw ? bv : av; vy = sw ? av : bv;
  ix = sw ? bi : ai; iy = sw ? ai : bi;
}

__device__ __forceinline__ float score7(const float4& qa, const float4& qb,
                                        const float4& A, const float4& B) {
  float s = qa.x * A.x;
  s = fmaf(qa.y, A.y, s);
  s = fmaf(qa.z, A.z, s);
  s = fmaf(qa.w, A.w, s);
  s = fmaf(qb.x, B.x, s);
  s = fmaf(qb.y, B.y, s);
  s = fmaf(-0.5f, B.z, s);
  return s;
}

template <bool SELF>
__device__ __forceinline__ void scan256(const float4* __restrict__ pp, int j0, int q,
    const float4 qa, const float4 qb,
    float& v0, float& v1, float& v2, int& i0, int& i1, int& i2) {
  for (int t = 0; t < 256; t += 4) {
    float4 A0 = pp[2 * t + 0], B0 = pp[2 * t + 1];
    float4 A1 = pp[2 * t + 2], B1 = pp[2 * t + 3];
    float4 A2 = pp[2 * t + 4], B2 = pp[2 * t + 5];
    float4 A3 = pp[2 * t + 6], B3 = pp[2 * t + 7];
    float s0 = score7(qa, qb, A0, B0);
    float s1 = score7(qa, qb, A1, B1);
    float s2 = score7(qa, qb, A2, B2);
    float s3 = score7(qa, qb, A3, B3);
    int jb = j0 + t;
    if (SELF) {
      if (jb + 0 == q) s0 = -INFINITY;
      if (jb + 1 == q) s1 = -INFINITY;
      if (jb + 2 == q) s2 = -INFINITY;
      if (jb + 3 == q) s3 = -INFINITY;
    }
    ins3(s0, jb + 0, v0, v1, v2, i0, i1, i2);
    ins3(s1, jb + 1, v0, v1, v2, i0, i1, i2);
    ins3(s2, jb + 2, v0, v1, v2, i0, i1, i2);
    ins3(s3, jb + 3, v0, v1, v2, i0, i1, i2);
  }
}

// ---------------------------------------------------------------------------
// Kernel 1: full KNN per block (round-4 exact). Block = 64 queries x 8 waves;
// wave w scans its 256-point segment (wave-uniform -> scalar loads). Self is
// always top-1 -> scan top-3 of j!=q, prepend q. LDS tree merge -> knn4.
// ---------------------------------------------------------------------------
__global__ __launch_bounds__(512) void knn_kernel(
    const float4* __restrict__ pts, int4* __restrict__ knn4) {
  __shared__ float4 lv[8][64];
  __shared__ int4   li[8][64];
  int lane = threadIdx.x & 63;
  int w = threadIdx.x >> 6;                 // segment 0..7
  int bk = blockIdx.x >> 5, qg = blockIdx.x & 31;
  int base = bk * NPT;
  int q = qg * 64 + lane;
  float4 qa = pts[(size_t)(base + q) * 2 + 0];
  float4 qb = pts[(size_t)(base + q) * 2 + 1];
  int j0 = __builtin_amdgcn_readfirstlane(w * 256);
  const float4* pp = pts + ((size_t)base + j0) * 2;
  float v0 = -INFINITY, v1 = -INFINITY, v2 = -INFINITY;
  int   i0 = 0x7fffffff, i1 = 0x7fffffff, i2 = 0x7fffffff;
  if (w == (qg >> 2)) scan256<true >(pp, j0, q, qa, qb, v0, v1, v2, i0, i1, i2);
  else                scan256<false>(pp, j0, q, qa, qb, v0, v1, v2, i0, i1, i2);
  lv[w][lane] = make_float4(v0, v1, v2, -INFINITY);
  li[w][lane] = make_int4(i0, i1, i2, 0x7fffffff);
  __syncthreads();
#pragma unroll
  for (int str = 4; str >= 1; str >>= 1) {
    if (w < str) {
      float4 av = lv[w][lane];        int4 ai = li[w][lane];
      float4 bv = lv[w + str][lane];  int4 bi = li[w + str][lane];
      float a0 = av.x, a1 = av.y, a2 = av.z, a3 = av.w;
      int   c0 = ai.x, c1 = ai.y, c2 = ai.z, c3 = ai.w;
      float s4 = bv.w, s5 = bv.z, s6 = bv.y, s7 = bv.x;
      int   t4 = bi.w, t5 = bi.z, t6 = bi.y, t7 = bi.x;
      ce(a0, c0, s4, t4); ce(a1, c1, s5, t5);
      ce(a2, c2, s6, t6); ce(a3, c3, s7, t7);
      ce(a0, c0, a2, c2); ce(a1, c1, a3, c3);
      ce(a0, c0, a1, c1); ce(a2, c2, a3, c3);
      lv[w][lane] = make_float4(a0, a1, a2, a3);
      li[w][lane] = make_int4(c0, c1, c2, c3);
    }
    __syncthreads();
  }
  if (w == 0) {
    int4 r = li[0][lane];
    knn4[base + q] = make_int4(q, r.x, r.y, r.z);
  }
}

// ---------------------------------------------------------------------------
// Kernel 2: 16 points/block, 128 thr, thread = (p 0..15, og 0..7), o = og+8m.
// h (kk-packed f4 in LDS) -> d1 (weights from global wpk) -> argmax k -> x1
// (overlaid into hlds) -> d3 -> dot3 (dlds) -> block argmax over 16 pts ->
// partials[bk][o][pb] = (x1, dot3)
// ---------------------------------------------------------------------------
__global__ __launch_bounds__(128) void feature_kernel(
    const float4* __restrict__ pts, const int4* __restrict__ knn4,
    const float* __restrict__ W1f, const float* __restrict__ W1d,
    const float4* __restrict__ wpk,
    float4* __restrict__ partials) {
  __shared__ float4 hlds[16][97];          // [p][c*3+j] f4 over kk; x1 overlay at [p][0..31]
  __shared__ float  dlds[16][33];          // [p][o] dot3
  int p = threadIdx.x >> 3;        // 0..15
  int og = threadIdx.x & 7;        // o = og + 8m
  int bk = blockIdx.x >> 7, pb = blockIdx.x & 127;
  int n = (pb << 4) | p;
  int base = bk * NPT;
  float4 ca = pts[(size_t)(base + n) * 2 + 0], cbv = pts[(size_t)(base + n) * 2 + 1];
  float ct[6] = {ca.x, ca.y, ca.z, ca.w, cbv.x, cbv.y};
  float w1f[4][4], w1d[4][4];
#pragma unroll
  for (int m = 0; m < 4; ++m) {
    float4 wf = reinterpret_cast<const float4*>(W1f)[og + 8 * m];
    float4 wd = reinterpret_cast<const float4*>(W1d)[og + 8 * m];
    w1f[m][0] = wf.x; w1f[m][1] = wf.y; w1f[m][2] = wf.z; w1f[m][3] = wf.w;
    w1d[m][0] = wd.x; w1d[m][1] = wd.y; w1d[m][2] = wd.z; w1d[m][3] = wd.w;
  }
  int4 nb = knn4[base + n];
  int nbi[4] = {nb.x, nb.y, nb.z, nb.w};
  float h[4][4][3];                // [m][kk][j]
#pragma unroll
  for (int kk = 0; kk < 4; ++kk) {
    int mi = nbi[kk];
    float4 A = pts[(size_t)(base + mi) * 2 + 0], B = pts[(size_t)(base + mi) * 2 + 1];
    float nc[6] = {A.x, A.y, A.z, A.w, B.x, B.y};
    float G[4][3];
#pragma unroll
    for (int j = 0; j < 3; ++j) {
      G[0][j] = nc[j] - ct[j];
      G[1][j] = nc[3 + j] - ct[3 + j];
      G[2][j] = ct[j];
      G[3][j] = ct[3 + j];
    }
#pragma unroll
    for (int m = 0; m < 4; ++m) {
      float pvv[3], dv[3];
#pragma unroll
      for (int j = 0; j < 3; ++j) {
        float a = 0.f, dd = 0.f;
#pragma unroll
        for (int c = 0; c < 4; ++c) { a = fmaf(w1f[m][c], G[c][j], a); dd = fmaf(w1d[m][c], G[c][j], dd); }
        pvv[j] = a; dv[j] = dd;
      }
      float dot = pvv[0] * dv[0] + pvv[1] * dv[1] + pvv[2] * dv[2];
      float d2  = dv[0] * dv[0] + dv[1] * dv[1] + dv[2] * dv[2];
      float fac = dot / (d2 + EPSF);
#pragma unroll
      for (int j = 0; j < 3; ++j) {
        float negj = pvv[j] - fac * dv[j];
        float sel = (dot >= 0.f) ? pvv[j] : negj;
        h[m][kk][j] = SLOPEF * pvv[j] + (1.f - SLOPEF) * sel;
      }
    }
  }
#pragma unroll
  for (int m = 0; m < 4; ++m)
#pragma unroll
    for (int j = 0; j < 3; ++j)
      hlds[p][(og + 8 * m) * 3 + j] =
          make_float4(h[m][0][j], h[m][1][j], h[m][2][j], h[m][3][j]);
  __syncthreads();
  // d1[m][j] (f4 over kk) = sum_c Wp1[og+8m][c] * h[c][kk][j]
  float4 d1j0[4], d1j1[4], d1j2[4];
#pragma unroll
  for (int m = 0; m < 4; ++m) {
    d1j0[m] = make_float4(0.f, 0.f, 0.f, 0.f);
    d1j1[m] = make_float4(0.f, 0.f, 0.f, 0.f);
    d1j2[m] = make_float4(0.f, 0.f, 0.f, 0.f);
  }
  for (int c = 0; c < 32; ++c) {
    float4 wv = wpk[c * 8 + og];
    float4 h0 = hlds[p][c * 3 + 0];
    float4 h1 = hlds[p][c * 3 + 1];
    float4 h2 = hlds[p][c * 3 + 2];
#pragma unroll
    for (int m = 0; m < 4; ++m) {
      float wm = COMP(wv, m);
      fma4(d1j0[m], wm, h0);
      fma4(d1j1[m], wm, h1);
      fma4(d1j2[m], wm, h2);
    }
  }
  // argmax over kk (first occurrence), per m
  float x1[4][3];
#pragma unroll
  for (int m = 0; m < 4; ++m) {
    float best = -INFINITY;
    float xa = 0.f, xb = 0.f, xc = 0.f;
#pragma unroll
    for (int kk = 0; kk < 4; ++kk) {
      float dt = h[m][kk][0] * COMP(d1j0[m], kk)
               + h[m][kk][1] * COMP(d1j1[m], kk)
               + h[m][kk][2] * COMP(d1j2[m], kk);
      if (dt > best) { best = dt; xa = h[m][kk][0]; xb = h[m][kk][1]; xc = h[m][kk][2]; }
    }
    x1[m][0] = xa; x1[m][1] = xb; x1[m][2] = xc;
  }
  __syncthreads();                  // all reads of h done -> overlay x1
#pragma unroll
  for (int m = 0; m < 4; ++m)
    hlds[p][og + 8 * m] = make_float4(x1[m][0], x1[m][1], x1[m][2], 0.f);
  __syncthreads();
  float d3[4][3] = {};
  for (int c = 0; c < 32; ++c) {
    float4 wv = wpk[256 + c * 8 + og];
    float4 xv = hlds[p][c];
#pragma unroll
    for (int m = 0; m < 4; ++m) {
      float wm = COMP(wv, m);
      d3[m][0] = fmaf(wm, xv.x, d3[m][0]);
      d3[m][1] = fmaf(wm, xv.y, d3[m][1]);
      d3[m][2] = fmaf(wm, xv.z, d3[m][2]);
    }
  }
#pragma unroll
  for (int m = 0; m < 4; ++m)
    dlds[p][og + 8 * m] = x1[m][0] * d3[m][0] + x1[m][1] * d3[m][1] + x1[m][2] * d3[m][2];
  __syncthreads();
  if (threadIdx.x < 32) {
    int o = threadIdx.x;
    float bd = -INFINITY; int wp_ = 0;
#pragma unroll
    for (int p2 = 0; p2 < 16; ++p2) {
      float dv = dlds[p2][o];
      if (dv > bd) { bd = dv; wp_ = p2; }      // strict '>': first n wins
    }
    float4 xv = hlds[wp_][o];
    partials[(((size_t)(bk * 32 + o)) << 7) | pb] = make_float4(xv.x, xv.y, xv.z, bd);
  }
}

// ---------------------------------------------------------------------------
// Kernel 3: per bk: argmax over 128 partials per o (first-index ties), then
// head: pk = Wh2 @ pooled ; +GS_EPS*noise ; Gram-Schmidt ; det flip
// ---------------------------------------------------------------------------
__global__ __launch_bounds__(256) void poolhead_kernel(
    const float4* __restrict__ partials, const float* __restrict__ Wh2,
    const float* __restrict__ gs, float* __restrict__ out) {
  __shared__ float pl[DIM][3];
  int bk = blockIdx.x;
  int o = threadIdx.x >> 3, tg = threadIdx.x & 7;
  const float4* pp = partials + (((size_t)(bk * 32 + o)) << 7);
  float best = -INFINITY; int bp = 0x7fffffff;
  for (int t = 0; t < 16; ++t) {
    int pb = t * 8 + tg;
    float v = pp[pb].w;
    if (v > best) { best = v; bp = pb; }       // strict '>' within residue class
  }
#pragma unroll
  for (int off = 1; off < 8; off <<= 1) {
    float ov = __shfl_xor(best, off, 8);
    int   op = __shfl_xor(bp, off, 8);
    if (ov > best || (ov == best && op < bp)) { best = ov; bp = op; }
  }
  if (tg == 0) {
    float4 xv = pp[bp];
    pl[o][0] = xv.x; pl[o][1] = xv.y; pl[o][2] = xv.z;
  }
  __syncthreads();
  if (threadIdx.x == 0) {
    float M[3][3];
#pragma unroll
    for (int oo = 0; oo < 3; ++oo) {
      float a0 = 0.f, a1 = 0.f, a2 = 0.f;
      for (int c = 0; c < 32; ++c) {
        float w = Wh2[oo * 32 + c];
        a0 = fmaf(w, pl[c][0], a0);
        a1 = fmaf(w, pl[c][1], a1);
        a2 = fmaf(w, pl[c][2], a2);
      }
      M[0][oo] = a0 + GS_EPSF * gs[bk * 9 + 0 * 3 + oo];
      M[1][oo] = a1 + GS_EPSF * gs[bk * 9 + 1 * 3 + oo];
      M[2][oo] = a2 + GS_EPSF * gs[bk * 9 + 2 * 3 + oo];
    }
    float e1[3], e2[3], e3[3], u[3];
    float nn = sqrtf(M[0][0] * M[0][0] + M[1][0] * M[1][0] + M[2][0] * M[2][0]) + EPSF;
#pragma unroll
    for (int r = 0; r < 3; ++r) e1[r] = M[r][0] / nn;
    float d12 = e1[0] * M[0][1] + e1[1] * M[1][1] + e1[2] * M[2][1];
#pragma unroll
    for (int r = 0; r < 3; ++r) u[r] = M[r][1] - d12 * e1[r];
    nn = sqrtf(u[0] * u[0] + u[1] * u[1] + u[2] * u[2]) + EPSF;
#pragma unroll
    for (int r = 0; r < 3; ++r) e2[r] = u[r] / nn;
    float d13 = e1[0] * M[0][2] + e1[1] * M[1][2] + e1[2] * M[2][2];
    float d23 = e2[0] * M[0][2] + e2[1] * M[1][2] + e2[2] * M[2][2];
#pragma unroll
    for (int r = 0; r < 3; ++r) u[r] = M[r][2] - d13 * e1[r] - d23 * e2[r];
    nn = sqrtf(u[0] * u[0] + u[1] * u[1] + u[2] * u[2]) + EPSF;
#pragma unroll
    for (int r = 0; r < 3; ++r) e3[r] = u[r] / nn;
    float det = e1[0] * (e2[1] * e3[2] - e2[2] * e3[1])
              - e1[1] * (e2[0] * e3[2] - e2[2] * e3[0])
              + e1[2] * (e2[0] * e3[1] - e2[1] * e3[0]);
#pragma unroll
    for (int r = 0; r < 3; ++r) {
      out[bk * 9 + r * 3 + 0] = e1[r] * det;
      out[bk * 9 + r * 3 + 1] = e2[r];
      out[bk * 9 + r * 3 + 2] = e3[r];
    }
  }
}

// ---------------------------------------------------------------------------
extern "C" void kernel_launch(void* const* d_in, const int* in_sizes, int n_in,
                              void* d_out, int out_size, void* d_ws, size_t ws_size,
                              hipStream_t stream) {
  (void)in_sizes; (void)n_in; (void)out_size; (void)ws_size;
  const float* node = (const float*)d_in[0];
  const float* W1f = (const float*)d_in[4];
  const float* W1d = (const float*)d_in[5];
  const float* Wp1 = (const float*)d_in[6];
  const float* Wp3 = (const float*)d_in[7];
  const float* Wh2 = (const float*)d_in[8];
  const float* z   = (const float*)d_in[9];
  const float* gs  = (const float*)d_in[10];

  float4* pts      = (float4*)d_ws;                          // 65536 f4 = 1 MB
  int4*   knn4     = (int4*)(pts + (size_t)BKT * NPT * 2);   // 512 KB
  float4* partials = (float4*)(knn4 + (size_t)BKT * NPT);    // 16*32*128 f4 = 1 MB
  float4* wpk      = partials + (size_t)BKT * 32 * 128;      // 512 f4 = 8 KB
  float*  out      = (float*)d_out;

  prep_coords    <<<BKT * NPT / 256, 256, 0, stream>>>(node, z, Wp1, Wp3, pts, wpk);
  knn_kernel     <<<BKT * 32, 512, 0, stream>>>(pts, knn4);
  feature_kernel <<<BKT * 128, 128, 0, stream>>>(pts, knn4, W1f, W1d, wpk, partials);
  poolhead_kernel<<<BKT, 256, 0, stream>>>(partials, Wh2, gs, out);
}

// Round 7
// 82.030 us; speedup vs baseline: 1.4906x; 1.0717x over previous
//
#include <hip/hip_runtime.h>
#include <math.h>

#define EPSF    1e-8f
#define SLOPEF  0.2f
#define GS_EPSF 1e-6f

#define NB   4
#define KZ   4
#define BKT  16     // NB*KZ
#define NPT  2048
#define DIM  32

#define COMP(v,kk) ((kk)==0?(v).x:(kk)==1?(v).y:(kk)==2?(v).z:(v).w)

__device__ __forceinline__ void fma4(float4& acc, float s, const float4& v) {
  acc.x = fmaf(s, v.x, acc.x); acc.y = fmaf(s, v.y, acc.y);
  acc.z = fmaf(s, v.z, acc.z); acc.w = fmaf(s, v.w, acc.w);
}

// ---------------------------------------------------------------------------
// Kernel 0: pts[bk*2048+n] = {A=(ch0..ch3), B=(ch4,ch5,xx,0)} interleaved.
// Block 0 additionally packs Wp1/Wp3 into wpk (f4 over m at [c*8+og]).
// ---------------------------------------------------------------------------
__global__ __launch_bounds__(256) void prep_coords(
    const float* __restrict__ node, const float* __restrict__ z,
    const float* __restrict__ Wp1, const float* __restrict__ Wp3,
    float4* __restrict__ pts, float4* __restrict__ wpk) {
  if (blockIdx.x == 0) {
    int i = threadIdx.x;                   // 256 entries each
    int og = i & 7, c = i >> 3;
    wpk[i]       = make_float4(Wp1[og * 32 + c], Wp1[(og + 8) * 32 + c],
                               Wp1[(og + 16) * 32 + c], Wp1[(og + 24) * 32 + c]);
    wpk[256 + i] = make_float4(Wp3[og * 32 + c], Wp3[(og + 8) * 32 + c],
                               Wp3[(og + 16) * 32 + c], Wp3[(og + 24) * 32 + c]);
  }
  int t = blockIdx.x * 256 + threadIdx.x;
  if (t >= BKT * NPT) return;
  int bk = t >> 11, n = t & (NPT - 1);
  int b = bk >> 2, kz = bk & 3;
  const float2* np2 = (const float2*)(node + (size_t)(b * NPT + n) * 6);
  const float2* zp2 = (const float2*)(z + (size_t)((b * KZ + kz) * NPT + n) * 6);
  float ch[6];
#pragma unroll
  for (int j = 0; j < 3; ++j) {
    float2 a = np2[j], c = zp2[j];
    ch[j]     = a.x + c.x;
    ch[3 + j] = a.y + c.y;
  }
  float xx = 0.f;
#pragma unroll
  for (int h = 0; h < 6; ++h) xx = fmaf(ch[h], ch[h], xx);
  pts[(size_t)t * 2 + 0] = make_float4(ch[0], ch[1], ch[2], ch[3]);
  pts[(size_t)t * 2 + 1] = make_float4(ch[4], ch[5], xx, 0.f);
}

// ---------------------------------------------------------------------------
// branchless sorted-insert of (s,j) into desc top-3; ascending-j + strict '>'
// ---------------------------------------------------------------------------
__device__ __forceinline__ void ins3(float s, int j,
    float& v0, float& v1, float& v2, int& i0, int& i1, int& i2) {
  bool c2 = s > v2;
  float nv2 = c2 ? s : v2; int ni2 = c2 ? j : i2;
  bool c1 = nv2 > v1;
  float u1v = c1 ? nv2 : v1, u2v = c1 ? v1 : nv2;
  int   u1i = c1 ? ni2 : i1, u2i = c1 ? i1 : ni2;
  bool c0 = u1v > v0;
  v1 = c0 ? v0 : u1v; i1 = c0 ? i0 : u1i;
  v0 = c0 ? u1v : v0; i0 = c0 ? u1i : i0;
  v2 = u2v; i2 = u2i;
}

// compare-exchange: total order (value desc, index asc)
__device__ __forceinline__ void ce(float& vx, int& ix, float& vy, int& iy) {
  float av = vx, bv = vy; int ai = ix, bi = iy;
  bool sw = (bv > av) || (bv == av && bi < ai);
  vx = sw ? bv : av; vy = sw ? av : bv;
  ix = sw ? bi : ai; iy = sw ? ai : bi;
}

__device__ __forceinline__ float score7(const float4& qa, const float4& qb,
                                        const float4& A, const float4& B) {
  float s = qa.x * A.x;
  s = fmaf(qa.y, A.y, s);
  s = fmaf(qa.z, A.z, s);
  s = fmaf(qa.w, A.w, s);
  s = fmaf(qb.x, B.x, s);
  s = fmaf(qb.y, B.y, s);
  s = fmaf(-0.5f, B.z, s);
  return s;
}

template <bool SELF>
__device__ __forceinline__ void scan128(const float4* __restrict__ pp, int j0, int q,
    const float4 qa, const float4 qb,
    float& v0, float& v1, float& v2, int& i0, int& i1, int& i2) {
  for (int t = 0; t < 128; t += 4) {
    float4 A0 = pp[2 * t + 0], B0 = pp[2 * t + 1];
    float4 A1 = pp[2 * t + 2], B1 = pp[2 * t + 3];
    float4 A2 = pp[2 * t + 4], B2 = pp[2 * t + 5];
    float4 A3 = pp[2 * t + 6], B3 = pp[2 * t + 7];
    float s0 = score7(qa, qb, A0, B0);
    float s1 = score7(qa, qb, A1, B1);
    float s2 = score7(qa, qb, A2, B2);
    float s3 = score7(qa, qb, A3, B3);
    int jb = j0 + t;
    if (SELF) {
      if (jb + 0 == q) s0 = -INFINITY;
      if (jb + 1 == q) s1 = -INFINITY;
      if (jb + 2 == q) s2 = -INFINITY;
      if (jb + 3 == q) s3 = -INFINITY;
    }
    ins3(s0, jb + 0, v0, v1, v2, i0, i1, i2);
    ins3(s1, jb + 1, v0, v1, v2, i0, i1, i2);
    ins3(s2, jb + 2, v0, v1, v2, i0, i1, i2);
    ins3(s3, jb + 3, v0, v1, v2, i0, i1, i2);
  }
}

// ---------------------------------------------------------------------------
// Kernel 1: full KNN per block. Block = 64 queries x 16 waves; wave w scans
// its 128-point segment (wave-uniform -> scalar loads). 8192 waves total =
// 32 waves/CU. Self is always top-1 -> scan top-3 of j!=q, prepend q.
// 4-round LDS tree merge -> knn4.
// ---------------------------------------------------------------------------
__global__ __launch_bounds__(1024) void knn_kernel(
    const float4* __restrict__ pts, int4* __restrict__ knn4) {
  __shared__ float4 lv[16][64];
  __shared__ int4   li[16][64];
  int lane = threadIdx.x & 63;
  int w = threadIdx.x >> 6;                 // segment 0..15
  int bk = blockIdx.x >> 5, qg = blockIdx.x & 31;
  int base = bk * NPT;
  int q = qg * 64 + lane;
  float4 qa = pts[(size_t)(base + q) * 2 + 0];
  float4 qb = pts[(size_t)(base + q) * 2 + 1];
  int j0 = __builtin_amdgcn_readfirstlane(w * 128);
  const float4* pp = pts + ((size_t)base + j0) * 2;
  float v0 = -INFINITY, v1 = -INFINITY, v2 = -INFINITY;
  int   i0 = 0x7fffffff, i1 = 0x7fffffff, i2 = 0x7fffffff;
  if (w == (qg >> 1)) scan128<true >(pp, j0, q, qa, qb, v0, v1, v2, i0, i1, i2);
  else                scan128<false>(pp, j0, q, qa, qb, v0, v1, v2, i0, i1, i2);
  lv[w][lane] = make_float4(v0, v1, v2, -INFINITY);
  li[w][lane] = make_int4(i0, i1, i2, 0x7fffffff);
  __syncthreads();
#pragma unroll
  for (int str = 8; str >= 1; str >>= 1) {
    if (w < str) {
      float4 av = lv[w][lane];        int4 ai = li[w][lane];
      float4 bv = lv[w + str][lane];  int4 bi = li[w + str][lane];
      float a0 = av.x, a1 = av.y, a2 = av.z, a3 = av.w;
      int   c0 = ai.x, c1 = ai.y, c2 = ai.z, c3 = ai.w;
      float s4 = bv.w, s5 = bv.z, s6 = bv.y, s7 = bv.x;
      int   t4 = bi.w, t5 = bi.z, t6 = bi.y, t7 = bi.x;
      ce(a0, c0, s4, t4); ce(a1, c1, s5, t5);
      ce(a2, c2, s6, t6); ce(a3, c3, s7, t7);
      ce(a0, c0, a2, c2); ce(a1, c1, a3, c3);
      ce(a0, c0, a1, c1); ce(a2, c2, a3, c3);
      lv[w][lane] = make_float4(a0, a1, a2, a3);
      li[w][lane] = make_int4(c0, c1, c2, c3);
    }
    __syncthreads();
  }
  if (w == 0) {
    int4 r = li[0][lane];
    knn4[base + q] = make_int4(q, r.x, r.y, r.z);
  }
}

// ---------------------------------------------------------------------------
// Kernel 2 (round-6 exact): 16 points/block, 128 thr, thread = (p, og),
// o = og+8m. h (kk-packed f4 in LDS) -> d1 (wpk from global) -> argmax k ->
// x1 (overlay) -> d3 -> dot3 -> block argmax -> partials[bk][o][pb]
// ---------------------------------------------------------------------------
__global__ __launch_bounds__(128) void feature_kernel(
    const float4* __restrict__ pts, const int4* __restrict__ knn4,
    const float* __restrict__ W1f, const float* __restrict__ W1d,
    const float4* __restrict__ wpk,
    float4* __restrict__ partials) {
  __shared__ float4 hlds[16][97];          // [p][c*3+j] f4 over kk; x1 overlay at [p][0..31]
  __shared__ float  dlds[16][33];          // [p][o] dot3
  int p = threadIdx.x >> 3;        // 0..15
  int og = threadIdx.x & 7;        // o = og + 8m
  int bk = blockIdx.x >> 7, pb = blockIdx.x & 127;
  int n = (pb << 4) | p;
  int base = bk * NPT;
  float4 ca = pts[(size_t)(base + n) * 2 + 0], cbv = pts[(size_t)(base + n) * 2 + 1];
  float ct[6] = {ca.x, ca.y, ca.z, ca.w, cbv.x, cbv.y};
  float w1f[4][4], w1d[4][4];
#pragma unroll
  for (int m = 0; m < 4; ++m) {
    float4 wf = reinterpret_cast<const float4*>(W1f)[og + 8 * m];
    float4 wd = reinterpret_cast<const float4*>(W1d)[og + 8 * m];
    w1f[m][0] = wf.x; w1f[m][1] = wf.y; w1f[m][2] = wf.z; w1f[m][3] = wf.w;
    w1d[m][0] = wd.x; w1d[m][1] = wd.y; w1d[m][2] = wd.z; w1d[m][3] = wd.w;
  }
  int4 nb = knn4[base + n];
  int nbi[4] = {nb.x, nb.y, nb.z, nb.w};
  float h[4][4][3];                // [m][kk][j]
#pragma unroll
  for (int kk = 0; kk < 4; ++kk) {
    int mi = nbi[kk];
    float4 A = pts[(size_t)(base + mi) * 2 + 0], B = pts[(size_t)(base + mi) * 2 + 1];
    float nc[6] = {A.x, A.y, A.z, A.w, B.x, B.y};
    float G[4][3];
#pragma unroll
    for (int j = 0; j < 3; ++j) {
      G[0][j] = nc[j] - ct[j];
      G[1][j] = nc[3 + j] - ct[3 + j];
      G[2][j] = ct[j];
      G[3][j] = ct[3 + j];
    }
#pragma unroll
    for (int m = 0; m < 4; ++m) {
      float pvv[3], dv[3];
#pragma unroll
      for (int j = 0; j < 3; ++j) {
        float a = 0.f, dd = 0.f;
#pragma unroll
        for (int c = 0; c < 4; ++c) { a = fmaf(w1f[m][c], G[c][j], a); dd = fmaf(w1d[m][c], G[c][j], dd); }
        pvv[j] = a; dv[j] = dd;
      }
      float dot = pvv[0] * dv[0] + pvv[1] * dv[1] + pvv[2] * dv[2];
      float d2  = dv[0] * dv[0] + dv[1] * dv[1] + dv[2] * dv[2];
      float fac = dot / (d2 + EPSF);
#pragma unroll
      for (int j = 0; j < 3; ++j) {
        float negj = pvv[j] - fac * dv[j];
        float sel = (dot >= 0.f) ? pvv[j] : negj;
        h[m][kk][j] = SLOPEF * pvv[j] + (1.f - SLOPEF) * sel;
      }
    }
  }
#pragma unroll
  for (int m = 0; m < 4; ++m)
#pragma unroll
    for (int j = 0; j < 3; ++j)
      hlds[p][(og + 8 * m) * 3 + j] =
          make_float4(h[m][0][j], h[m][1][j], h[m][2][j], h[m][3][j]);
  __syncthreads();
  float4 d1j0[4], d1j1[4], d1j2[4];
#pragma unroll
  for (int m = 0; m < 4; ++m) {
    d1j0[m] = make_float4(0.f, 0.f, 0.f, 0.f);
    d1j1[m] = make_float4(0.f, 0.f, 0.f, 0.f);
    d1j2[m] = make_float4(0.f, 0.f, 0.f, 0.f);
  }
  for (int c = 0; c < 32; ++c) {
    float4 wv = wpk[c * 8 + og];
    float4 h0 = hlds[p][c * 3 + 0];
    float4 h1 = hlds[p][c * 3 + 1];
    float4 h2 = hlds[p][c * 3 + 2];
#pragma unroll
    for (int m = 0; m < 4; ++m) {
      float wm = COMP(wv, m);
      fma4(d1j0[m], wm, h0);
      fma4(d1j1[m], wm, h1);
      fma4(d1j2[m], wm, h2);
    }
  }
  float x1[4][3];
#pragma unroll
  for (int m = 0; m < 4; ++m) {
    float best = -INFINITY;
    float xa = 0.f, xb = 0.f, xc = 0.f;
#pragma unroll
    for (int kk = 0; kk < 4; ++kk) {
      float dt = h[m][kk][0] * COMP(d1j0[m], kk)
               + h[m][kk][1] * COMP(d1j1[m], kk)
               + h[m][kk][2] * COMP(d1j2[m], kk);
      if (dt > best) { best = dt; xa = h[m][kk][0]; xb = h[m][kk][1]; xc = h[m][kk][2]; }
    }
    x1[m][0] = xa; x1[m][1] = xb; x1[m][2] = xc;
  }
  __syncthreads();                  // all reads of h done -> overlay x1
#pragma unroll
  for (int m = 0; m < 4; ++m)
    hlds[p][og + 8 * m] = make_float4(x1[m][0], x1[m][1], x1[m][2], 0.f);
  __syncthreads();
  float d3[4][3] = {};
  for (int c = 0; c < 32; ++c) {
    float4 wv = wpk[256 + c * 8 + og];
    float4 xv = hlds[p][c];
#pragma unroll
    for (int m = 0; m < 4; ++m) {
      float wm = COMP(wv, m);
      d3[m][0] = fmaf(wm, xv.x, d3[m][0]);
      d3[m][1] = fmaf(wm, xv.y, d3[m][1]);
      d3[m][2] = fmaf(wm, xv.z, d3[m][2]);
    }
  }
#pragma unroll
  for (int m = 0; m < 4; ++m)
    dlds[p][og + 8 * m] = x1[m][0] * d3[m][0] + x1[m][1] * d3[m][1] + x1[m][2] * d3[m][2];
  __syncthreads();
  if (threadIdx.x < 32) {
    int o = threadIdx.x;
    float bd = -INFINITY; int wp_ = 0;
#pragma unroll
    for (int p2 = 0; p2 < 16; ++p2) {
      float dv = dlds[p2][o];
      if (dv > bd) { bd = dv; wp_ = p2; }      // strict '>': first n wins
    }
    float4 xv = hlds[wp_][o];
    partials[(((size_t)(bk * 32 + o)) << 7) | pb] = make_float4(xv.x, xv.y, xv.z, bd);
  }
}

// ---------------------------------------------------------------------------
// Kernel 3: per bk: argmax over 128 partials per o (first-index ties), then
// head: pk = Wh2 @ pooled ; +GS_EPS*noise ; Gram-Schmidt ; det flip
// ---------------------------------------------------------------------------
__global__ __launch_bounds__(256) void poolhead_kernel(
    const float4* __restrict__ partials, const float* __restrict__ Wh2,
    const float* __restrict__ gs, float* __restrict__ out) {
  __shared__ float pl[DIM][3];
  int bk = blockIdx.x;
  int o = threadIdx.x >> 3, tg = threadIdx.x & 7;
  const float4* pp = partials + (((size_t)(bk * 32 + o)) << 7);
  float best = -INFINITY; int bp = 0x7fffffff;
  for (int t = 0; t < 16; ++t) {
    int pb = t * 8 + tg;
    float v = pp[pb].w;
    if (v > best) { best = v; bp = pb; }       // strict '>' within residue class
  }
#pragma unroll
  for (int off = 1; off < 8; off <<= 1) {
    float ov = __shfl_xor(best, off, 8);
    int   op = __shfl_xor(bp, off, 8);
    if (ov > best || (ov == best && op < bp)) { best = ov; bp = op; }
  }
  if (tg == 0) {
    float4 xv = pp[bp];
    pl[o][0] = xv.x; pl[o][1] = xv.y; pl[o][2] = xv.z;
  }
  __syncthreads();
  if (threadIdx.x == 0) {
    float M[3][3];
#pragma unroll
    for (int oo = 0; oo < 3; ++oo) {
      float a0 = 0.f, a1 = 0.f, a2 = 0.f;
      for (int c = 0; c < 32; ++c) {
        float w = Wh2[oo * 32 + c];
        a0 = fmaf(w, pl[c][0], a0);
        a1 = fmaf(w, pl[c][1], a1);
        a2 = fmaf(w, pl[c][2], a2);
      }
      M[0][oo] = a0 + GS_EPSF * gs[bk * 9 + 0 * 3 + oo];
      M[1][oo] = a1 + GS_EPSF * gs[bk * 9 + 1 * 3 + oo];
      M[2][oo] = a2 + GS_EPSF * gs[bk * 9 + 2 * 3 + oo];
    }
    float e1[3], e2[3], e3[3], u[3];
    float nn = sqrtf(M[0][0] * M[0][0] + M[1][0] * M[1][0] + M[2][0] * M[2][0]) + EPSF;
#pragma unroll
    for (int r = 0; r < 3; ++r) e1[r] = M[r][0] / nn;
    float d12 = e1[0] * M[0][1] + e1[1] * M[1][1] + e1[2] * M[2][1];
#pragma unroll
    for (int r = 0; r < 3; ++r) u[r] = M[r][1] - d12 * e1[r];
    nn = sqrtf(u[0] * u[0] + u[1] * u[1] + u[2] * u[2]) + EPSF;
#pragma unroll
    for (int r = 0; r < 3; ++r) e2[r] = u[r] / nn;
    float d13 = e1[0] * M[0][2] + e1[1] * M[1][2] + e1[2] * M[2][2];
    float d23 = e2[0] * M[0][2] + e2[1] * M[1][2] + e2[2] * M[2][2];
#pragma unroll
    for (int r = 0; r < 3; ++r) u[r] = M[r][2] - d13 * e1[r] - d23 * e2[r];
    nn = sqrtf(u[0] * u[0] + u[1] * u[1] + u[2] * u[2]) + EPSF;
#pragma unroll
    for (int r = 0; r < 3; ++r) e3[r] = u[r] / nn;
    float det = e1[0] * (e2[1] * e3[2] - e2[2] * e3[1])
              - e1[1] * (e2[0] * e3[2] - e2[2] * e3[0])
              + e1[2] * (e2[0] * e3[1] - e2[1] * e3[0]);
#pragma unroll
    for (int r = 0; r < 3; ++r) {
      out[bk * 9 + r * 3 + 0] = e1[r] * det;
      out[bk * 9 + r * 3 + 1] = e2[r];
      out[bk * 9 + r * 3 + 2] = e3[r];
    }
  }
}

// ---------------------------------------------------------------------------
extern "C" void kernel_launch(void* const* d_in, const int* in_sizes, int n_in,
                              void* d_out, int out_size, void* d_ws, size_t ws_size,
                              hipStream_t stream) {
  (void)in_sizes; (void)n_in; (void)out_size; (void)ws_size;
  const float* node = (const float*)d_in[0];
  const float* W1f = (const float*)d_in[4];
  const float* W1d = (const float*)d_in[5];
  const float* Wp1 = (const float*)d_in[6];
  const float* Wp3 = (const float*)d_in[7];
  const float* Wh2 = (const float*)d_in[8];
  const float* z   = (const float*)d_in[9];
  const float* gs  = (const float*)d_in[10];

  float4* pts      = (float4*)d_ws;                          // 65536 f4 = 1 MB
  int4*   knn4     = (int4*)(pts + (size_t)BKT * NPT * 2);   // 512 KB
  float4* partials = (float4*)(knn4 + (size_t)BKT * NPT);    // 16*32*128 f4 = 1 MB
  float4* wpk      = partials + (size_t)BKT * 32 * 128;      // 512 f4 = 8 KB
  float*  out      = (float*)d_out;

  prep_coords    <<<BKT * NPT / 256, 256, 0, stream>>>(node, z, Wp1, Wp3, pts, wpk);
  knn_kernel     <<<BKT * 32, 1024, 0, stream>>>(pts, knn4);
  feature_kernel <<<BKT * 128, 128, 0, stream>>>(pts, knn4, W1f, W1d, wpk, partials);
  poolhead_kernel<<<BKT, 256, 0, stream>>>(partials, Wh2, gs, out);
}

// Round 8
// 80.131 us; speedup vs baseline: 1.5259x; 1.0237x over previous
//
#include <hip/hip_runtime.h>
#include <math.h>

#define EPSF    1e-8f
#define SLOPEF  0.2f
#define GS_EPSF 1e-6f

#define NB   4
#define KZ   4
#define BKT  16     // NB*KZ
#define NPT  2048
#define DIM  32

#define COMP(v,kk) ((kk)==0?(v).x:(kk)==1?(v).y:(kk)==2?(v).z:(v).w)

typedef float f2 __attribute__((ext_vector_type(2)));

__device__ __forceinline__ void fma4(float4& acc, float s, const float4& v) {
  acc.x = fmaf(s, v.x, acc.x); acc.y = fmaf(s, v.y, acc.y);
  acc.z = fmaf(s, v.z, acc.z); acc.w = fmaf(s, v.w, acc.w);
}

// ---------------------------------------------------------------------------
// Kernel 0: pts[bk*2048+n] = {A=(ch0..ch3), B=(ch4,ch5,xx,0)} interleaved AoS
// (for queries + feature gathers) AND ptsP pair-packed (for the knn scan):
// per point-pair p=(2t,2t+1): dwords [x0 x1 y0 y1 z0 z1 w0 w1 u0 u1 v0 v1
// xx0 xx1 - -]. Block 0 also packs Wp1/Wp3 into wpk.
// ---------------------------------------------------------------------------
__global__ __launch_bounds__(256) void prep_coords(
    const float* __restrict__ node, const float* __restrict__ z,
    const float* __restrict__ Wp1, const float* __restrict__ Wp3,
    float4* __restrict__ pts, float* __restrict__ ptsPf,
    float4* __restrict__ wpk) {
  if (blockIdx.x == 0) {
    int i = threadIdx.x;                   // 256 entries each
    int og = i & 7, c = i >> 3;
    wpk[i]       = make_float4(Wp1[og * 32 + c], Wp1[(og + 8) * 32 + c],
                               Wp1[(og + 16) * 32 + c], Wp1[(og + 24) * 32 + c]);
    wpk[256 + i] = make_float4(Wp3[og * 32 + c], Wp3[(og + 8) * 32 + c],
                               Wp3[(og + 16) * 32 + c], Wp3[(og + 24) * 32 + c]);
  }
  int t = blockIdx.x * 256 + threadIdx.x;
  if (t >= BKT * NPT) return;
  int bk = t >> 11, n = t & (NPT - 1);
  int b = bk >> 2, kz = bk & 3;
  const float2* np2 = (const float2*)(node + (size_t)(b * NPT + n) * 6);
  const float2* zp2 = (const float2*)(z + (size_t)((b * KZ + kz) * NPT + n) * 6);
  float ch[6];
#pragma unroll
  for (int j = 0; j < 3; ++j) {
    float2 a = np2[j], c = zp2[j];
    ch[j]     = a.x + c.x;
    ch[3 + j] = a.y + c.y;
  }
  float xx = 0.f;
#pragma unroll
  for (int h = 0; h < 6; ++h) xx = fmaf(ch[h], ch[h], xx);
  pts[(size_t)t * 2 + 0] = make_float4(ch[0], ch[1], ch[2], ch[3]);
  pts[(size_t)t * 2 + 1] = make_float4(ch[4], ch[5], xx, 0.f);
  // pair-packed copy
  size_t pbase = (size_t)(t >> 1) * 16 + (t & 1);
#pragma unroll
  for (int c = 0; c < 6; ++c) ptsPf[pbase + c * 2] = ch[c];
  ptsPf[pbase + 12] = xx;
}

// ---------------------------------------------------------------------------
// branchless top-3 insert via max/med3 for values + 3 cmp / 5 sel for indices.
// Ascending-j scan + strict '>' => first-index tie semantics (verified vs the
// shift-chain ins3 on all orderings incl. exact ties and -INF warm-up).
// ---------------------------------------------------------------------------
__device__ __forceinline__ void ins3m(float s, int j,
    float& v0, float& v1, float& v2, int& i0, int& i1, int& i2) {
  bool c0 = s > v0, c1 = s > v1, c2 = s > v2;
  float nv0 = fmaxf(v0, s);
  float nv1 = __builtin_amdgcn_fmed3f(v0, v1, s);
  float nv2 = __builtin_amdgcn_fmed3f(v1, v2, s);
  i2 = c1 ? i1 : (c2 ? j : i2);
  i1 = c0 ? i0 : (c1 ? j : i1);
  i0 = c0 ? j : i0;
  v0 = nv0; v1 = nv1; v2 = nv2;
}

// compare-exchange: total order (value desc, index asc)
__device__ __forceinline__ void ce(float& vx, int& ix, float& vy, int& iy) {
  float av = vx, bv = vy; int ai = ix, bi = iy;
  bool sw = (bv > av) || (bv == av && bi < ai);
  vx = sw ? bv : av; vy = sw ? av : bv;
  ix = sw ? bi : ai; iy = sw ? ai : bi;
}

// ---------------------------------------------------------------------------
// Packed 128-point scan: 2 pairs (4 candidates) per iteration; scores for a
// pair computed with 7 VOP3P packed ops (bit-exact vs scalar chain).
// ---------------------------------------------------------------------------
template <bool SELF>
__device__ __forceinline__ void scan128P(const float4* __restrict__ pp4,
    int j0, int q, const float4 qa, const float4 qb,
    float& v0, float& v1, float& v2, int& i0, int& i1, int& i2) {
  f2 qx = {qa.x, qa.x}, qy = {qa.y, qa.y}, qz = {qa.z, qa.z}, qw = {qa.w, qa.w};
  f2 qu = {qb.x, qb.x}, qv = {qb.y, qb.y}, mh = {-0.5f, -0.5f};
  const f2* pp2 = (const f2*)pp4;
  for (int pr = 0; pr < 64; pr += 2) {
    float4 L0a = pp4[pr * 4 + 0], L1a = pp4[pr * 4 + 1], L2a = pp4[pr * 4 + 2];
    f2 Xa = pp2[pr * 8 + 6];
    float4 L0b = pp4[pr * 4 + 4], L1b = pp4[pr * 4 + 5], L2b = pp4[pr * 4 + 6];
    f2 Xb = pp2[pr * 8 + 14];
    f2 ax = {L0a.x, L0a.y}, ay = {L0a.z, L0a.w};
    f2 az = {L1a.x, L1a.y}, aw = {L1a.z, L1a.w};
    f2 au = {L2a.x, L2a.y}, av = {L2a.z, L2a.w};
    f2 sa = qx * ax;
    sa = __builtin_elementwise_fma(qy, ay, sa);
    sa = __builtin_elementwise_fma(qz, az, sa);
    sa = __builtin_elementwise_fma(qw, aw, sa);
    sa = __builtin_elementwise_fma(qu, au, sa);
    sa = __builtin_elementwise_fma(qv, av, sa);
    sa = __builtin_elementwise_fma(mh, Xa, sa);
    f2 bx = {L0b.x, L0b.y}, by = {L0b.z, L0b.w};
    f2 bz = {L1b.x, L1b.y}, bw = {L1b.z, L1b.w};
    f2 bu = {L2b.x, L2b.y}, bv = {L2b.z, L2b.w};
    f2 sb = qx * bx;
    sb = __builtin_elementwise_fma(qy, by, sb);
    sb = __builtin_elementwise_fma(qz, bz, sb);
    sb = __builtin_elementwise_fma(qw, bw, sb);
    sb = __builtin_elementwise_fma(qu, bu, sb);
    sb = __builtin_elementwise_fma(qv, bv, sb);
    sb = __builtin_elementwise_fma(mh, Xb, sb);
    int jb = j0 + 2 * pr;
    float s0 = sa.x, s1 = sa.y, s2 = sb.x, s3 = sb.y;
    if (SELF) {
      if (jb + 0 == q) s0 = -INFINITY;
      if (jb + 1 == q) s1 = -INFINITY;
      if (jb + 2 == q) s2 = -INFINITY;
      if (jb + 3 == q) s3 = -INFINITY;
    }
    ins3m(s0, jb + 0, v0, v1, v2, i0, i1, i2);
    ins3m(s1, jb + 1, v0, v1, v2, i0, i1, i2);
    ins3m(s2, jb + 2, v0, v1, v2, i0, i1, i2);
    ins3m(s3, jb + 3, v0, v1, v2, i0, i1, i2);
  }
}

// ---------------------------------------------------------------------------
// Kernel 1: full KNN per block. Block = 64 queries x 16 waves; wave w scans
// its 128-point segment from ptsP (wave-uniform addresses). Self is always
// top-1 -> scan top-3 of j!=q, prepend q. 4-round LDS tree merge -> knn4.
// ---------------------------------------------------------------------------
__global__ __launch_bounds__(1024) void knn_kernel(
    const float4* __restrict__ pts, const float4* __restrict__ ptsP,
    int4* __restrict__ knn4) {
  __shared__ float4 lv[16][64];
  __shared__ int4   li[16][64];
  int lane = threadIdx.x & 63;
  int w = threadIdx.x >> 6;                 // segment 0..15
  int bk = blockIdx.x >> 5, qg = blockIdx.x & 31;
  int base = bk * NPT;
  int q = qg * 64 + lane;
  float4 qa = pts[(size_t)(base + q) * 2 + 0];
  float4 qb = pts[(size_t)(base + q) * 2 + 1];
  int j0 = __builtin_amdgcn_readfirstlane(w * 128);
  const float4* pp4 = ptsP + ((size_t)(base + j0) >> 1) * 4;
  float v0 = -INFINITY, v1 = -INFINITY, v2 = -INFINITY;
  int   i0 = 0x7fffffff, i1 = 0x7fffffff, i2 = 0x7fffffff;
  if (w == (qg >> 1)) scan128P<true >(pp4, j0, q, qa, qb, v0, v1, v2, i0, i1, i2);
  else                scan128P<false>(pp4, j0, q, qa, qb, v0, v1, v2, i0, i1, i2);
  lv[w][lane] = make_float4(v0, v1, v2, -INFINITY);
  li[w][lane] = make_int4(i0, i1, i2, 0x7fffffff);
  __syncthreads();
#pragma unroll
  for (int str = 8; str >= 1; str >>= 1) {
    if (w < str) {
      float4 av = lv[w][lane];        int4 ai = li[w][lane];
      float4 bv = lv[w + str][lane];  int4 bi = li[w + str][lane];
      float a0 = av.x, a1 = av.y, a2 = av.z, a3 = av.w;
      int   c0 = ai.x, c1 = ai.y, c2 = ai.z, c3 = ai.w;
      float s4 = bv.w, s5 = bv.z, s6 = bv.y, s7 = bv.x;
      int   t4 = bi.w, t5 = bi.z, t6 = bi.y, t7 = bi.x;
      ce(a0, c0, s4, t4); ce(a1, c1, s5, t5);
      ce(a2, c2, s6, t6); ce(a3, c3, s7, t7);
      ce(a0, c0, a2, c2); ce(a1, c1, a3, c3);
      ce(a0, c0, a1, c1); ce(a2, c2, a3, c3);
      lv[w][lane] = make_float4(a0, a1, a2, a3);
      li[w][lane] = make_int4(c0, c1, c2, c3);
    }
    __syncthreads();
  }
  if (w == 0) {
    int4 r = li[0][lane];
    knn4[base + q] = make_int4(q, r.x, r.y, r.z);
  }
}

// ---------------------------------------------------------------------------
// Kernel 2 (round-6/7 exact): 16 points/block, 128 thr, thread = (p, og),
// o = og+8m. h (kk-packed f4 in LDS) -> d1 (wpk from global) -> argmax k ->
// x1 (overlay) -> d3 -> dot3 -> block argmax -> partials[bk][o][pb]
// ---------------------------------------------------------------------------
__global__ __launch_bounds__(128) void feature_kernel(
    const float4* __restrict__ pts, const int4* __restrict__ knn4,
    const float* __restrict__ W1f, const float* __restrict__ W1d,
    const float4* __restrict__ wpk,
    float4* __restrict__ partials) {
  __shared__ float4 hlds[16][97];          // [p][c*3+j] f4 over kk; x1 overlay at [p][0..31]
  __shared__ float  dlds[16][33];          // [p][o] dot3
  int p = threadIdx.x >> 3;        // 0..15
  int og = threadIdx.x & 7;        // o = og + 8m
  int bk = blockIdx.x >> 7, pb = blockIdx.x & 127;
  int n = (pb << 4) | p;
  int base = bk * NPT;
  float4 ca = pts[(size_t)(base + n) * 2 + 0], cbv = pts[(size_t)(base + n) * 2 + 1];
  float ct[6] = {ca.x, ca.y, ca.z, ca.w, cbv.x, cbv.y};
  float w1f[4][4], w1d[4][4];
#pragma unroll
  for (int m = 0; m < 4; ++m) {
    float4 wf = reinterpret_cast<const float4*>(W1f)[og + 8 * m];
    float4 wd = reinterpret_cast<const float4*>(W1d)[og + 8 * m];
    w1f[m][0] = wf.x; w1f[m][1] = wf.y; w1f[m][2] = wf.z; w1f[m][3] = wf.w;
    w1d[m][0] = wd.x; w1d[m][1] = wd.y; w1d[m][2] = wd.z; w1d[m][3] = wd.w;
  }
  int4 nb = knn4[base + n];
  int nbi[4] = {nb.x, nb.y, nb.z, nb.w};
  float h[4][4][3];                // [m][kk][j]
#pragma unroll
  for (int kk = 0; kk < 4; ++kk) {
    int mi = nbi[kk];
    float4 A = pts[(size_t)(base + mi) * 2 + 0], B = pts[(size_t)(base + mi) * 2 + 1];
    float nc[6] = {A.x, A.y, A.z, A.w, B.x, B.y};
    float G[4][3];
#pragma unroll
    for (int j = 0; j < 3; ++j) {
      G[0][j] = nc[j] - ct[j];
      G[1][j] = nc[3 + j] - ct[3 + j];
      G[2][j] = ct[j];
      G[3][j] = ct[3 + j];
    }
#pragma unroll
    for (int m = 0; m < 4; ++m) {
      float pvv[3], dv[3];
#pragma unroll
      for (int j = 0; j < 3; ++j) {
        float a = 0.f, dd = 0.f;
#pragma unroll
        for (int c = 0; c < 4; ++c) { a = fmaf(w1f[m][c], G[c][j], a); dd = fmaf(w1d[m][c], G[c][j], dd); }
        pvv[j] = a; dv[j] = dd;
      }
      float dot = pvv[0] * dv[0] + pvv[1] * dv[1] + pvv[2] * dv[2];
      float d2  = dv[0] * dv[0] + dv[1] * dv[1] + dv[2] * dv[2];
      float fac = dot / (d2 + EPSF);
#pragma unroll
      for (int j = 0; j < 3; ++j) {
        float negj = pvv[j] - fac * dv[j];
        float sel = (dot >= 0.f) ? pvv[j] : negj;
        h[m][kk][j] = SLOPEF * pvv[j] + (1.f - SLOPEF) * sel;
      }
    }
  }
#pragma unroll
  for (int m = 0; m < 4; ++m)
#pragma unroll
    for (int j = 0; j < 3; ++j)
      hlds[p][(og + 8 * m) * 3 + j] =
          make_float4(h[m][0][j], h[m][1][j], h[m][2][j], h[m][3][j]);
  __syncthreads();
  float4 d1j0[4], d1j1[4], d1j2[4];
#pragma unroll
  for (int m = 0; m < 4; ++m) {
    d1j0[m] = make_float4(0.f, 0.f, 0.f, 0.f);
    d1j1[m] = make_float4(0.f, 0.f, 0.f, 0.f);
    d1j2[m] = make_float4(0.f, 0.f, 0.f, 0.f);
  }
  for (int c = 0; c < 32; ++c) {
    float4 wv = wpk[c * 8 + og];
    float4 h0 = hlds[p][c * 3 + 0];
    float4 h1 = hlds[p][c * 3 + 1];
    float4 h2 = hlds[p][c * 3 + 2];
#pragma unroll
    for (int m = 0; m < 4; ++m) {
      float wm = COMP(wv, m);
      fma4(d1j0[m], wm, h0);
      fma4(d1j1[m], wm, h1);
      fma4(d1j2[m], wm, h2);
    }
  }
  float x1[4][3];
#pragma unroll
  for (int m = 0; m < 4; ++m) {
    float best = -INFINITY;
    float xa = 0.f, xb = 0.f, xc = 0.f;
#pragma unroll
    for (int kk = 0; kk < 4; ++kk) {
      float dt = h[m][kk][0] * COMP(d1j0[m], kk)
               + h[m][kk][1] * COMP(d1j1[m], kk)
               + h[m][kk][2] * COMP(d1j2[m], kk);
      if (dt > best) { best = dt; xa = h[m][kk][0]; xb = h[m][kk][1]; xc = h[m][kk][2]; }
    }
    x1[m][0] = xa; x1[m][1] = xb; x1[m][2] = xc;
  }
  __syncthreads();                  // all reads of h done -> overlay x1
#pragma unroll
  for (int m = 0; m < 4; ++m)
    hlds[p][og + 8 * m] = make_float4(x1[m][0], x1[m][1], x1[m][2], 0.f);
  __syncthreads();
  float d3[4][3] = {};
  for (int c = 0; c < 32; ++c) {
    float4 wv = wpk[256 + c * 8 + og];
    float4 xv = hlds[p][c];
#pragma unroll
    for (int m = 0; m < 4; ++m) {
      float wm = COMP(wv, m);
      d3[m][0] = fmaf(wm, xv.x, d3[m][0]);
      d3[m][1] = fmaf(wm, xv.y, d3[m][1]);
      d3[m][2] = fmaf(wm, xv.z, d3[m][2]);
    }
  }
#pragma unroll
  for (int m = 0; m < 4; ++m)
    dlds[p][og + 8 * m] = x1[m][0] * d3[m][0] + x1[m][1] * d3[m][1] + x1[m][2] * d3[m][2];
  __syncthreads();
  if (threadIdx.x < 32) {
    int o = threadIdx.x;
    float bd = -INFINITY; int wp_ = 0;
#pragma unroll
    for (int p2 = 0; p2 < 16; ++p2) {
      float dv = dlds[p2][o];
      if (dv > bd) { bd = dv; wp_ = p2; }      // strict '>': first n wins
    }
    float4 xv = hlds[wp_][o];
    partials[(((size_t)(bk * 32 + o)) << 7) | pb] = make_float4(xv.x, xv.y, xv.z, bd);
  }
}

// ---------------------------------------------------------------------------
// Kernel 3: per bk: argmax over 128 partials per o (first-index ties), then
// head: pk = Wh2 @ pooled ; +GS_EPS*noise ; Gram-Schmidt ; det flip
// ---------------------------------------------------------------------------
__global__ __launch_bounds__(256) void poolhead_kernel(
    const float4* __restrict__ partials, const float* __restrict__ Wh2,
    const float* __restrict__ gs, float* __restrict__ out) {
  __shared__ float pl[DIM][3];
  int bk = blockIdx.x;
  int o = threadIdx.x >> 3, tg = threadIdx.x & 7;
  const float4* pp = partials + (((size_t)(bk * 32 + o)) << 7);
  float best = -INFINITY; int bp = 0x7fffffff;
  for (int t = 0; t < 16; ++t) {
    int pb = t * 8 + tg;
    float v = pp[pb].w;
    if (v > best) { best = v; bp = pb; }       // strict '>' within residue class
  }
#pragma unroll
  for (int off = 1; off < 8; off <<= 1) {
    float ov = __shfl_xor(best, off, 8);
    int   op = __shfl_xor(bp, off, 8);
    if (ov > best || (ov == best && op < bp)) { best = ov; bp = op; }
  }
  if (tg == 0) {
    float4 xv = pp[bp];
    pl[o][0] = xv.x; pl[o][1] = xv.y; pl[o][2] = xv.z;
  }
  __syncthreads();
  if (threadIdx.x == 0) {
    float M[3][3];
#pragma unroll
    for (int oo = 0; oo < 3; ++oo) {
      float a0 = 0.f, a1 = 0.f, a2 = 0.f;
      for (int c = 0; c < 32; ++c) {
        float w = Wh2[oo * 32 + c];
        a0 = fmaf(w, pl[c][0], a0);
        a1 = fmaf(w, pl[c][1], a1);
        a2 = fmaf(w, pl[c][2], a2);
      }
      M[0][oo] = a0 + GS_EPSF * gs[bk * 9 + 0 * 3 + oo];
      M[1][oo] = a1 + GS_EPSF * gs[bk * 9 + 1 * 3 + oo];
      M[2][oo] = a2 + GS_EPSF * gs[bk * 9 + 2 * 3 + oo];
    }
    float e1[3], e2[3], e3[3], u[3];
    float nn = sqrtf(M[0][0] * M[0][0] + M[1][0] * M[1][0] + M[2][0] * M[2][0]) + EPSF;
#pragma unroll
    for (int r = 0; r < 3; ++r) e1[r] = M[r][0] / nn;
    float d12 = e1[0] * M[0][1] + e1[1] * M[1][1] + e1[2] * M[2][1];
#pragma unroll
    for (int r = 0; r < 3; ++r) u[r] = M[r][1] - d12 * e1[r];
    nn = sqrtf(u[0] * u[0] + u[1] * u[1] + u[2] * u[2]) + EPSF;
#pragma unroll
    for (int r = 0; r < 3; ++r) e2[r] = u[r] / nn;
    float d13 = e1[0] * M[0][2] + e1[1] * M[1][2] + e1[2] * M[2][2];
    float d23 = e2[0] * M[0][2] + e2[1] * M[1][2] + e2[2] * M[2][2];
#pragma unroll
    for (int r = 0; r < 3; ++r) u[r] = M[r][2] - d13 * e1[r] - d23 * e2[r];
    nn = sqrtf(u[0] * u[0] + u[1] * u[1] + u[2] * u[2]) + EPSF;
#pragma unroll
    for (int r = 0; r < 3; ++r) e3[r] = u[r] / nn;
    float det = e1[0] * (e2[1] * e3[2] - e2[2] * e3[1])
              - e1[1] * (e2[0] * e3[2] - e2[2] * e3[0])
              + e1[2] * (e2[0] * e3[1] - e2[1] * e3[0]);
#pragma unroll
    for (int r = 0; r < 3; ++r) {
      out[bk * 9 + r * 3 + 0] = e1[r] * det;
      out[bk * 9 + r * 3 + 1] = e2[r];
      out[bk * 9 + r * 3 + 2] = e3[r];
    }
  }
}

// ---------------------------------------------------------------------------
extern "C" void kernel_launch(void* const* d_in, const int* in_sizes, int n_in,
                              void* d_out, int out_size, void* d_ws, size_t ws_size,
                              hipStream_t stream) {
  (void)in_sizes; (void)n_in; (void)out_size; (void)ws_size;
  const float* node = (const float*)d_in[0];
  const float* W1f = (const float*)d_in[4];
  const float* W1d = (const float*)d_in[5];
  const float* Wp1 = (const float*)d_in[6];
  const float* Wp3 = (const float*)d_in[7];
  const float* Wh2 = (const float*)d_in[8];
  const float* z   = (const float*)d_in[9];
  const float* gs  = (const float*)d_in[10];

  float4* pts      = (float4*)d_ws;                          // 65536 f4 = 1 MB
  int4*   knn4     = (int4*)(pts + (size_t)BKT * NPT * 2);   // 512 KB
  float4* partials = (float4*)(knn4 + (size_t)BKT * NPT);    // 16*32*128 f4 = 1 MB
  float4* wpk      = partials + (size_t)BKT * 32 * 128;      // 512 f4 = 8 KB
  float4* ptsP     = wpk + 512;                              // 16384 pairs * 4 f4 = 1 MB
  float*  out      = (float*)d_out;

  prep_coords    <<<BKT * NPT / 256, 256, 0, stream>>>(node, z, Wp1, Wp3, pts,
                                                       (float*)ptsP, wpk);
  knn_kernel     <<<BKT * 32, 1024, 0, stream>>>(pts, ptsP, knn4);
  feature_kernel <<<BKT * 128, 128, 0, stream>>>(pts, knn4, W1f, W1d, wpk, partials);
  poolhead_kernel<<<BKT, 256, 0, stream>>>(partials, Wh2, gs, out);
}

// Round 9
// 79.630 us; speedup vs baseline: 1.5355x; 1.0063x over previous
//
#include <hip/hip_runtime.h>
#include <math.h>

#define EPSF    1e-8f
#define SLOPEF  0.2f
#define GS_EPSF 1e-6f

#define NB   4
#define KZ   4
#define BKT  16     // NB*KZ
#define NPT  2048
#define DIM  32

#define COMP(v,kk) ((kk)==0?(v).x:(kk)==1?(v).y:(kk)==2?(v).z:(v).w)

typedef float f2 __attribute__((ext_vector_type(2)));

__device__ __forceinline__ void fma4(float4& acc, float s, const float4& v) {
  acc.x = fmaf(s, v.x, acc.x); acc.y = fmaf(s, v.y, acc.y);
  acc.z = fmaf(s, v.z, acc.z); acc.w = fmaf(s, v.w, acc.w);
}

// ---------------------------------------------------------------------------
// Kernel 0: pts[bk*2048+n] = {A=(ch0..ch3), B=(ch4,ch5,xx,0)} interleaved AoS
// (queries + feature gathers) AND ptsP pair-packed (knn scan): per point-pair
// p=(2t,2t+1): dwords [x0 x1 y0 y1 | z0 z1 w0 w1 | u0 u1 v0 v1 | xx0 xx1 - -].
// Block 0 also packs Wp1/Wp3 into wpk.
// ---------------------------------------------------------------------------
__global__ __launch_bounds__(256) void prep_coords(
    const float* __restrict__ node, const float* __restrict__ z,
    const float* __restrict__ Wp1, const float* __restrict__ Wp3,
    float4* __restrict__ pts, float* __restrict__ ptsPf,
    float4* __restrict__ wpk) {
  if (blockIdx.x == 0) {
    int i = threadIdx.x;                   // 256 entries each
    int og = i & 7, c = i >> 3;
    wpk[i]       = make_float4(Wp1[og * 32 + c], Wp1[(og + 8) * 32 + c],
                               Wp1[(og + 16) * 32 + c], Wp1[(og + 24) * 32 + c]);
    wpk[256 + i] = make_float4(Wp3[og * 32 + c], Wp3[(og + 8) * 32 + c],
                               Wp3[(og + 16) * 32 + c], Wp3[(og + 24) * 32 + c]);
  }
  int t = blockIdx.x * 256 + threadIdx.x;
  if (t >= BKT * NPT) return;
  int bk = t >> 11, n = t & (NPT - 1);
  int b = bk >> 2, kz = bk & 3;
  const float2* np2 = (const float2*)(node + (size_t)(b * NPT + n) * 6);
  const float2* zp2 = (const float2*)(z + (size_t)((b * KZ + kz) * NPT + n) * 6);
  float ch[6];
#pragma unroll
  for (int j = 0; j < 3; ++j) {
    float2 a = np2[j], c = zp2[j];
    ch[j]     = a.x + c.x;
    ch[3 + j] = a.y + c.y;
  }
  float xx = 0.f;
#pragma unroll
  for (int h = 0; h < 6; ++h) xx = fmaf(ch[h], ch[h], xx);
  pts[(size_t)t * 2 + 0] = make_float4(ch[0], ch[1], ch[2], ch[3]);
  pts[(size_t)t * 2 + 1] = make_float4(ch[4], ch[5], xx, 0.f);
  // pair-packed copy
  size_t pbase = (size_t)(t >> 1) * 16 + (t & 1);
#pragma unroll
  for (int c = 0; c < 6; ++c) ptsPf[pbase + c * 2] = ch[c];
  ptsPf[pbase + 12] = xx;
}

// ---------------------------------------------------------------------------
// branchless top-3 insert via max/med3 for values + 3 cmp / 5 sel for indices.
// Ascending-j scan + strict '>' => first-index tie semantics.
// ---------------------------------------------------------------------------
__device__ __forceinline__ void ins3m(float s, int j,
    float& v0, float& v1, float& v2, int& i0, int& i1, int& i2) {
  bool c0 = s > v0, c1 = s > v1, c2 = s > v2;
  float nv0 = fmaxf(v0, s);
  float nv1 = __builtin_amdgcn_fmed3f(v0, v1, s);
  float nv2 = __builtin_amdgcn_fmed3f(v1, v2, s);
  i2 = c1 ? i1 : (c2 ? j : i2);
  i1 = c0 ? i0 : (c1 ? j : i1);
  i0 = c0 ? j : i0;
  v0 = nv0; v1 = nv1; v2 = nv2;
}

// compare-exchange: total order (value desc, index asc)
__device__ __forceinline__ void ce(float& vx, int& ix, float& vy, int& iy) {
  float av = vx, bv = vy; int ai = ix, bi = iy;
  bool sw = (bv > av) || (bv == av && bi < ai);
  vx = sw ? bv : av; vy = sw ? av : bv;
  ix = sw ? bi : ai; iy = sw ? ai : bi;
}

// ---------------------------------------------------------------------------
// Register-lean 128-point scan: ONE pair (2 candidates) per iteration, 4
// dwordx4 scalar loads per pair record; unroll-2 lets the compiler pipeline
// two pairs under the 64-VGPR cap. Score chain order bit-identical to r8.
// ---------------------------------------------------------------------------
template <bool SELF>
__device__ __forceinline__ void scan128P(const float4* __restrict__ pp4,
    int j0, int q, const float4 qa, const float4 qb,
    float& v0, float& v1, float& v2, int& i0, int& i1, int& i2) {
  f2 qx = {qa.x, qa.x}, qy = {qa.y, qa.y}, qz = {qa.z, qa.z}, qw = {qa.w, qa.w};
  f2 qu = {qb.x, qb.x}, qv = {qb.y, qb.y}, mh = {-0.5f, -0.5f};
#pragma unroll 2
  for (int pr = 0; pr < 64; ++pr) {
    float4 L0 = pp4[pr * 4 + 0], L1 = pp4[pr * 4 + 1];
    float4 L2 = pp4[pr * 4 + 2], L3 = pp4[pr * 4 + 3];
    f2 ax = {L0.x, L0.y}, ay = {L0.z, L0.w};
    f2 az = {L1.x, L1.y}, aw = {L1.z, L1.w};
    f2 au = {L2.x, L2.y}, av = {L2.z, L2.w};
    f2 Xa = {L3.x, L3.y};
    f2 sa = qx * ax;
    sa = __builtin_elementwise_fma(qy, ay, sa);
    sa = __builtin_elementwise_fma(qz, az, sa);
    sa = __builtin_elementwise_fma(qw, aw, sa);
    sa = __builtin_elementwise_fma(qu, au, sa);
    sa = __builtin_elementwise_fma(qv, av, sa);
    sa = __builtin_elementwise_fma(mh, Xa, sa);
    int jb = j0 + 2 * pr;
    float s0 = sa.x, s1 = sa.y;
    if (SELF) {
      if (jb + 0 == q) s0 = -INFINITY;
      if (jb + 1 == q) s1 = -INFINITY;
    }
    ins3m(s0, jb + 0, v0, v1, v2, i0, i1, i2);
    ins3m(s1, jb + 1, v0, v1, v2, i0, i1, i2);
  }
}

// ---------------------------------------------------------------------------
// Kernel 1: full KNN per block. Block = 64 queries x 16 waves; wave w scans
// its 128-point segment from ptsP (wave-uniform -> scalar loads). min-waves
// clause forces VGPR<=64 so TWO 16-wave blocks co-reside per CU (32 waves/CU).
// Self is always top-1 -> scan top-3 of j!=q, prepend q. 4-round merge.
// ---------------------------------------------------------------------------
__global__ __launch_bounds__(1024, 8) void knn_kernel(
    const float4* __restrict__ pts, const float4* __restrict__ ptsP,
    int4* __restrict__ knn4) {
  __shared__ float4 lv[16][64];
  __shared__ int4   li[16][64];
  int lane = threadIdx.x & 63;
  int w = threadIdx.x >> 6;                 // segment 0..15
  int bk = blockIdx.x >> 5, qg = blockIdx.x & 31;
  int base = bk * NPT;
  int q = qg * 64 + lane;
  float4 qa = pts[(size_t)(base + q) * 2 + 0];
  float4 qb = pts[(size_t)(base + q) * 2 + 1];
  int j0 = __builtin_amdgcn_readfirstlane(w * 128);
  const float4* pp4 = ptsP + ((size_t)(base + j0) >> 1) * 4;
  float v0 = -INFINITY, v1 = -INFINITY, v2 = -INFINITY;
  int   i0 = 0x7fffffff, i1 = 0x7fffffff, i2 = 0x7fffffff;
  if (w == (qg >> 1)) scan128P<true >(pp4, j0, q, qa, qb, v0, v1, v2, i0, i1, i2);
  else                scan128P<false>(pp4, j0, q, qa, qb, v0, v1, v2, i0, i1, i2);
  lv[w][lane] = make_float4(v0, v1, v2, -INFINITY);
  li[w][lane] = make_int4(i0, i1, i2, 0x7fffffff);
  __syncthreads();
#pragma unroll
  for (int str = 8; str >= 1; str >>= 1) {
    if (w < str) {
      float4 av = lv[w][lane];        int4 ai = li[w][lane];
      float4 bv = lv[w + str][lane];  int4 bi = li[w + str][lane];
      float a0 = av.x, a1 = av.y, a2 = av.z, a3 = av.w;
      int   c0 = ai.x, c1 = ai.y, c2 = ai.z, c3 = ai.w;
      float s4 = bv.w, s5 = bv.z, s6 = bv.y, s7 = bv.x;
      int   t4 = bi.w, t5 = bi.z, t6 = bi.y, t7 = bi.x;
      ce(a0, c0, s4, t4); ce(a1, c1, s5, t5);
      ce(a2, c2, s6, t6); ce(a3, c3, s7, t7);
      ce(a0, c0, a2, c2); ce(a1, c1, a3, c3);
      ce(a0, c0, a1, c1); ce(a2, c2, a3, c3);
      lv[w][lane] = make_float4(a0, a1, a2, a3);
      li[w][lane] = make_int4(c0, c1, c2, c3);
    }
    __syncthreads();
  }
  if (w == 0) {
    int4 r = li[0][lane];
    knn4[base + q] = make_int4(q, r.x, r.y, r.z);
  }
}

// ---------------------------------------------------------------------------
// Kernel 2 (round-8 exact): 16 points/block, 128 thr, thread = (p, og),
// o = og+8m. h (kk-packed f4 in LDS) -> d1 (wpk from global) -> argmax k ->
// x1 (overlay) -> d3 -> dot3 -> block argmax -> partials[bk][o][pb]
// ---------------------------------------------------------------------------
__global__ __launch_bounds__(128) void feature_kernel(
    const float4* __restrict__ pts, const int4* __restrict__ knn4,
    const float* __restrict__ W1f, const float* __restrict__ W1d,
    const float4* __restrict__ wpk,
    float4* __restrict__ partials) {
  __shared__ float4 hlds[16][97];          // [p][c*3+j] f4 over kk; x1 overlay at [p][0..31]
  __shared__ float  dlds[16][33];          // [p][o] dot3
  int p = threadIdx.x >> 3;        // 0..15
  int og = threadIdx.x & 7;        // o = og + 8m
  int bk = blockIdx.x >> 7, pb = blockIdx.x & 127;
  int n = (pb << 4) | p;
  int base = bk * NPT;
  float4 ca = pts[(size_t)(base + n) * 2 + 0], cbv = pts[(size_t)(base + n) * 2 + 1];
  float ct[6] = {ca.x, ca.y, ca.z, ca.w, cbv.x, cbv.y};
  float w1f[4][4], w1d[4][4];
#pragma unroll
  for (int m = 0; m < 4; ++m) {
    float4 wf = reinterpret_cast<const float4*>(W1f)[og + 8 * m];
    float4 wd = reinterpret_cast<const float4*>(W1d)[og + 8 * m];
    w1f[m][0] = wf.x; w1f[m][1] = wf.y; w1f[m][2] = wf.z; w1f[m][3] = wf.w;
    w1d[m][0] = wd.x; w1d[m][1] = wd.y; w1d[m][2] = wd.z; w1d[m][3] = wd.w;
  }
  int4 nb = knn4[base + n];
  int nbi[4] = {nb.x, nb.y, nb.z, nb.w};
  float h[4][4][3];                // [m][kk][j]
#pragma unroll
  for (int kk = 0; kk < 4; ++kk) {
    int mi = nbi[kk];
    float4 A = pts[(size_t)(base + mi) * 2 + 0], B = pts[(size_t)(base + mi) * 2 + 1];
    float nc[6] = {A.x, A.y, A.z, A.w, B.x, B.y};
    float G[4][3];
#pragma unroll
    for (int j = 0; j < 3; ++j) {
      G[0][j] = nc[j] - ct[j];
      G[1][j] = nc[3 + j] - ct[3 + j];
      G[2][j] = ct[j];
      G[3][j] = ct[3 + j];
    }
#pragma unroll
    for (int m = 0; m < 4; ++m) {
      float pvv[3], dv[3];
#pragma unroll
      for (int j = 0; j < 3; ++j) {
        float a = 0.f, dd = 0.f;
#pragma unroll
        for (int c = 0; c < 4; ++c) { a = fmaf(w1f[m][c], G[c][j], a); dd = fmaf(w1d[m][c], G[c][j], dd); }
        pvv[j] = a; dv[j] = dd;
      }
      float dot = pvv[0] * dv[0] + pvv[1] * dv[1] + pvv[2] * dv[2];
      float d2  = dv[0] * dv[0] + dv[1] * dv[1] + dv[2] * dv[2];
      float fac = dot / (d2 + EPSF);
#pragma unroll
      for (int j = 0; j < 3; ++j) {
        float negj = pvv[j] - fac * dv[j];
        float sel = (dot >= 0.f) ? pvv[j] : negj;
        h[m][kk][j] = SLOPEF * pvv[j] + (1.f - SLOPEF) * sel;
      }
    }
  }
#pragma unroll
  for (int m = 0; m < 4; ++m)
#pragma unroll
    for (int j = 0; j < 3; ++j)
      hlds[p][(og + 8 * m) * 3 + j] =
          make_float4(h[m][0][j], h[m][1][j], h[m][2][j], h[m][3][j]);
  __syncthreads();
  float4 d1j0[4], d1j1[4], d1j2[4];
#pragma unroll
  for (int m = 0; m < 4; ++m) {
    d1j0[m] = make_float4(0.f, 0.f, 0.f, 0.f);
    d1j1[m] = make_float4(0.f, 0.f, 0.f, 0.f);
    d1j2[m] = make_float4(0.f, 0.f, 0.f, 0.f);
  }
  for (int c = 0; c < 32; ++c) {
    float4 wv = wpk[c * 8 + og];
    float4 h0 = hlds[p][c * 3 + 0];
    float4 h1 = hlds[p][c * 3 + 1];
    float4 h2 = hlds[p][c * 3 + 2];
#pragma unroll
    for (int m = 0; m < 4; ++m) {
      float wm = COMP(wv, m);
      fma4(d1j0[m], wm, h0);
      fma4(d1j1[m], wm, h1);
      fma4(d1j2[m], wm, h2);
    }
  }
  float x1[4][3];
#pragma unroll
  for (int m = 0; m < 4; ++m) {
    float best = -INFINITY;
    float xa = 0.f, xb = 0.f, xc = 0.f;
#pragma unroll
    for (int kk = 0; kk < 4; ++kk) {
      float dt = h[m][kk][0] * COMP(d1j0[m], kk)
               + h[m][kk][1] * COMP(d1j1[m], kk)
               + h[m][kk][2] * COMP(d1j2[m], kk);
      if (dt > best) { best = dt; xa = h[m][kk][0]; xb = h[m][kk][1]; xc = h[m][kk][2]; }
    }
    x1[m][0] = xa; x1[m][1] = xb; x1[m][2] = xc;
  }
  __syncthreads();                  // all reads of h done -> overlay x1
#pragma unroll
  for (int m = 0; m < 4; ++m)
    hlds[p][og + 8 * m] = make_float4(x1[m][0], x1[m][1], x1[m][2], 0.f);
  __syncthreads();
  float d3[4][3] = {};
  for (int c = 0; c < 32; ++c) {
    float4 wv = wpk[256 + c * 8 + og];
    float4 xv = hlds[p][c];
#pragma unroll
    for (int m = 0; m < 4; ++m) {
      float wm = COMP(wv, m);
      d3[m][0] = fmaf(wm, xv.x, d3[m][0]);
      d3[m][1] = fmaf(wm, xv.y, d3[m][1]);
      d3[m][2] = fmaf(wm, xv.z, d3[m][2]);
    }
  }
#pragma unroll
  for (int m = 0; m < 4; ++m)
    dlds[p][og + 8 * m] = x1[m][0] * d3[m][0] + x1[m][1] * d3[m][1] + x1[m][2] * d3[m][2];
  __syncthreads();
  if (threadIdx.x < 32) {
    int o = threadIdx.x;
    float bd = -INFINITY; int wp_ = 0;
#pragma unroll
    for (int p2 = 0; p2 < 16; ++p2) {
      float dv = dlds[p2][o];
      if (dv > bd) { bd = dv; wp_ = p2; }      // strict '>': first n wins
    }
    float4 xv = hlds[wp_][o];
    partials[(((size_t)(bk * 32 + o)) << 7) | pb] = make_float4(xv.x, xv.y, xv.z, bd);
  }
}

// ---------------------------------------------------------------------------
// Kernel 3: per bk: argmax over 128 partials per o (first-index ties), then
// head: pk = Wh2 @ pooled ; +GS_EPS*noise ; Gram-Schmidt ; det flip
// ---------------------------------------------------------------------------
__global__ __launch_bounds__(256) void poolhead_kernel(
    const float4* __restrict__ partials, const float* __restrict__ Wh2,
    const float* __restrict__ gs, float* __restrict__ out) {
  __shared__ float pl[DIM][3];
  int bk = blockIdx.x;
  int o = threadIdx.x >> 3, tg = threadIdx.x & 7;
  const float4* pp = partials + (((size_t)(bk * 32 + o)) << 7);
  float best = -INFINITY; int bp = 0x7fffffff;
  for (int t = 0; t < 16; ++t) {
    int pb = t * 8 + tg;
    float v = pp[pb].w;
    if (v > best) { best = v; bp = pb; }       // strict '>' within residue class
  }
#pragma unroll
  for (int off = 1; off < 8; off <<= 1) {
    float ov = __shfl_xor(best, off, 8);
    int   op = __shfl_xor(bp, off, 8);
    if (ov > best || (ov == best && op < bp)) { best = ov; bp = op; }
  }
  if (tg == 0) {
    float4 xv = pp[bp];
    pl[o][0] = xv.x; pl[o][1] = xv.y; pl[o][2] = xv.z;
  }
  __syncthreads();
  if (threadIdx.x == 0) {
    float M[3][3];
#pragma unroll
    for (int oo = 0; oo < 3; ++oo) {
      float a0 = 0.f, a1 = 0.f, a2 = 0.f;
      for (int c = 0; c < 32; ++c) {
        float w = Wh2[oo * 32 + c];
        a0 = fmaf(w, pl[c][0], a0);
        a1 = fmaf(w, pl[c][1], a1);
        a2 = fmaf(w, pl[c][2], a2);
      }
      M[0][oo] = a0 + GS_EPSF * gs[bk * 9 + 0 * 3 + oo];
      M[1][oo] = a1 + GS_EPSF * gs[bk * 9 + 1 * 3 + oo];
      M[2][oo] = a2 + GS_EPSF * gs[bk * 9 + 2 * 3 + oo];
    }
    float e1[3], e2[3], e3[3], u[3];
    float nn = sqrtf(M[0][0] * M[0][0] + M[1][0] * M[1][0] + M[2][0] * M[2][0]) + EPSF;
#pragma unroll
    for (int r = 0; r < 3; ++r) e1[r] = M[r][0] / nn;
    float d12 = e1[0] * M[0][1] + e1[1] * M[1][1] + e1[2] * M[2][1];
#pragma unroll
    for (int r = 0; r < 3; ++r) u[r] = M[r][1] - d12 * e1[r];
    nn = sqrtf(u[0] * u[0] + u[1] * u[1] + u[2] * u[2]) + EPSF;
#pragma unroll
    for (int r = 0; r < 3; ++r) e2[r] = u[r] / nn;
    float d13 = e1[0] * M[0][2] + e1[1] * M[1][2] + e1[2] * M[2][2];
    float d23 = e2[0] * M[0][2] + e2[1] * M[1][2] + e2[2] * M[2][2];
#pragma unroll
    for (int r = 0; r < 3; ++r) u[r] = M[r][2] - d13 * e1[r] - d23 * e2[r];
    nn = sqrtf(u[0] * u[0] + u[1] * u[1] + u[2] * u[2]) + EPSF;
#pragma unroll
    for (int r = 0; r < 3; ++r) e3[r] = u[r] / nn;
    float det = e1[0] * (e2[1] * e3[2] - e2[2] * e3[1])
              - e1[1] * (e2[0] * e3[2] - e2[2] * e3[0])
              + e1[2] * (e2[0] * e3[1] - e2[1] * e3[0]);
#pragma unroll
    for (int r = 0; r < 3; ++r) {
      out[bk * 9 + r * 3 + 0] = e1[r] * det;
      out[bk * 9 + r * 3 + 1] = e2[r];
      out[bk * 9 + r * 3 + 2] = e3[r];
    }
  }
}

// ---------------------------------------------------------------------------
extern "C" void kernel_launch(void* const* d_in, const int* in_sizes, int n_in,
                              void* d_out, int out_size, void* d_ws, size_t ws_size,
                              hipStream_t stream) {
  (void)in_sizes; (void)n_in; (void)out_size; (void)ws_size;
  const float* node = (const float*)d_in[0];
  const float* W1f = (const float*)d_in[4];
  const float* W1d = (const float*)d_in[5];
  const float* Wp1 = (const float*)d_in[6];
  const float* Wp3 = (const float*)d_in[7];
  const float* Wh2 = (const float*)d_in[8];
  const float* z   = (const float*)d_in[9];
  const float* gs  = (const float*)d_in[10];

  float4* pts      = (float4*)d_ws;                          // 65536 f4 = 1 MB
  int4*   knn4     = (int4*)(pts + (size_t)BKT * NPT * 2);   // 512 KB
  float4* partials = (float4*)(knn4 + (size_t)BKT * NPT);    // 16*32*128 f4 = 1 MB
  float4* wpk      = partials + (size_t)BKT * 32 * 128;      // 512 f4 = 8 KB
  float4* ptsP     = wpk + 512;                              // 16384 pairs * 4 f4 = 1 MB
  float*  out      = (float*)d_out;

  prep_coords    <<<BKT * NPT / 256, 256, 0, stream>>>(node, z, Wp1, Wp3, pts,
                                                       (float*)ptsP, wpk);
  knn_kernel     <<<BKT * 32, 1024, 0, stream>>>(pts, ptsP, knn4);
  feature_kernel <<<BKT * 128, 128, 0, stream>>>(pts, knn4, W1f, W1d, wpk, partials);
  poolhead_kernel<<<BKT, 256, 0, stream>>>(partials, Wh2, gs, out);
}